// Round 2
// baseline (635.598 us; speedup 1.0000x reference)
//
#include <hip/hip_runtime.h>

// GraphPooling: voxel-grid pooling.
//  inputs: x[N,64] f32, pos[N,3] f32, edge_index[E,2] i32, batch[N] i32
//  outputs (concat, f32): pooled_x[M,64], pos_mean[M,3], ei_out[Ed+M,2], new_batch[M]
// Keyspace: key = ((b*s0+qx)*s1+qy)*s2+qz < 16*32*32*32 = 524288.
// Pooling: voxel-sorted point permutation (ptOrder) + one-wave-per-voxel segment
// reduce (coalesced 256B row reads) — no global atomics on the output.
// Edge pipeline: partition by src>>9 (1024 partitions, ~5.8k edges each),
// per-partition LDS counting-sort by srcLow + element-parallel rank-sort by dst,
// global (in-partition) dedup flag + block scan compaction.
// Codes packed as (src<<19)|dst (38 bits); in-LDS code28 = (srcLow<<19)|dst.

#define KSP 524288
#define SCAN_BLOCK 256
#define SCAN_ITEMS 16
#define SCAN_CHUNK 4096            // SCAN_BLOCK * SCAN_ITEMS
#define NCHUNK (KSP / SCAN_CHUNK)  // 128
#define NPART 1024
#define PB 512                     // voxel ranks per partition (KSP/NPART)
#define SCAP2 8192                 // LDS cap: edges per partition (mean ~5.8k, sigma ~150)

// ws header slots (u32): [0..2]=max qpos, [3]=M, [4]=validE, [5]=Ed, [6]=scratch total

// ---- per-point: max of quantized coords ----
__global__ void k_qmax(const float* __restrict__ pos, unsigned* hdr, int N) {
  __shared__ unsigned sm[3];
  if (threadIdx.x < 3) sm[threadIdx.x] = 0;
  __syncthreads();
  int i = blockIdx.x * blockDim.x + threadIdx.x;
  if (i < N) {
    int q0 = (int)floorf(pos[3 * i + 0] * 0.25f);
    int q1 = (int)floorf(pos[3 * i + 1] * 0.25f);
    int q2 = (int)floorf(pos[3 * i + 2] * 0.25f);
    atomicMax(&sm[0], (unsigned)q0);
    atomicMax(&sm[1], (unsigned)q1);
    atomicMax(&sm[2], (unsigned)q2);
  }
  __syncthreads();
  if (threadIdx.x < 3) atomicMax(&hdr[threadIdx.x], sm[threadIdx.x]);
}

// ---- per-point: voxel key + histogram ----
__global__ void k_keys(const float* __restrict__ pos, const int* __restrict__ batch,
                       const unsigned* __restrict__ hdr, unsigned* __restrict__ key,
                       unsigned* __restrict__ cnt, int N) {
  int i = blockIdx.x * blockDim.x + threadIdx.x;
  if (i >= N) return;
  unsigned s0 = hdr[0] + 1, s1 = hdr[1] + 1, s2 = hdr[2] + 1;
  unsigned q0 = (unsigned)(int)floorf(pos[3 * i + 0] * 0.25f);
  unsigned q1 = (unsigned)(int)floorf(pos[3 * i + 1] * 0.25f);
  unsigned q2 = (unsigned)(int)floorf(pos[3 * i + 2] * 0.25f);
  unsigned k = (((unsigned)batch[i] * s0 + q0) * s1 + q1) * s2 + q2;
  key[i] = k;
  atomicAdd(&cnt[k], 1u);
}

// ---- 3-phase exclusive scan over KSP ----
__global__ void scanA(const unsigned* __restrict__ in, unsigned* __restrict__ out,
                      unsigned* __restrict__ chunkSums, int n, int presence) {
  __shared__ unsigned lds[SCAN_BLOCK];
  int tbase = blockIdx.x * SCAN_CHUNK + threadIdx.x * SCAN_ITEMS;
  unsigned vals[SCAN_ITEMS];
  unsigned sum = 0;
  for (int i = 0; i < SCAN_ITEMS; ++i) {
    unsigned v = 0;
    int idx = tbase + i;
    if (idx < n) { v = in[idx]; if (presence) v = v ? 1u : 0u; }
    vals[i] = sum;
    sum += v;
  }
  lds[threadIdx.x] = sum;
  __syncthreads();
  for (int off = 1; off < SCAN_BLOCK; off <<= 1) {
    unsigned t = (threadIdx.x >= (unsigned)off) ? lds[threadIdx.x - off] : 0u;
    __syncthreads();
    lds[threadIdx.x] += t;
    __syncthreads();
  }
  unsigned threadExcl = lds[threadIdx.x] - sum;
  for (int i = 0; i < SCAN_ITEMS; ++i) {
    int idx = tbase + i;
    if (idx < n) out[idx] = threadExcl + vals[i];
  }
  if (threadIdx.x == SCAN_BLOCK - 1) chunkSums[blockIdx.x] = lds[SCAN_BLOCK - 1];
}

__global__ void scanB(unsigned* chunkSums, unsigned* totalDst, int nchunks) {
  __shared__ unsigned lds[1024];
  unsigned v = (threadIdx.x < (unsigned)nchunks) ? chunkSums[threadIdx.x] : 0u;
  lds[threadIdx.x] = v;
  __syncthreads();
  for (int off = 1; off < 1024; off <<= 1) {
    unsigned t = (threadIdx.x >= (unsigned)off) ? lds[threadIdx.x - off] : 0u;
    __syncthreads();
    lds[threadIdx.x] += t;
    __syncthreads();
  }
  if (threadIdx.x < (unsigned)nchunks) chunkSums[threadIdx.x] = lds[threadIdx.x] - v;
  if (threadIdx.x == 0 && totalDst) *totalDst = lds[1023];
}

__global__ void scanC(unsigned* __restrict__ out, unsigned* __restrict__ out2,
                      const unsigned* __restrict__ chunkSums, int n) {
  int idx = blockIdx.x * blockDim.x + threadIdx.x;
  if (idx >= n) return;
  unsigned v = out[idx] + chunkSums[idx / SCAN_CHUNK];
  out[idx] = v;
  if (out2) out2[idx] = v;
}

// ---- single-block exclusive scan of NPART entries ----
__global__ void k_scan1024(const unsigned* __restrict__ in, unsigned* __restrict__ outStart,
                           unsigned* __restrict__ outCursor, unsigned* __restrict__ totalDst) {
  __shared__ unsigned lds[NPART];
  unsigned t = threadIdx.x;
  unsigned v = in[t];
  lds[t] = v;
  __syncthreads();
  for (int off = 1; off < NPART; off <<= 1) {
    unsigned x = (t >= (unsigned)off) ? lds[t - off] : 0u;
    __syncthreads();
    lds[t] += x;
    __syncthreads();
  }
  unsigned excl = lds[t] - v;
  outStart[t] = excl;
  if (outCursor) outCursor[t] = excl;
  if (t == NPART - 1) {
    outStart[NPART] = lds[t];
    if (totalDst) *totalDst = lds[t];
  }
}

// ---- build rank -> key map ----
__global__ void k_ukey(const unsigned* __restrict__ cnt, const unsigned* __restrict__ rank,
                       unsigned* __restrict__ ukeyArr) {
  int k = blockIdx.x * blockDim.x + threadIdx.x;
  if (k >= KSP) return;
  if (cnt[k]) ukeyArr[rank[k]] = (unsigned)k;
}

// ---- per-point: inv index + voxel-sorted permutation ----
__global__ void k_scatter(const unsigned* __restrict__ key, const unsigned* __restrict__ rank,
                          unsigned* __restrict__ inv, unsigned* __restrict__ ptCursor,
                          unsigned* __restrict__ ptOrder, int N) {
  int i = blockIdx.x * blockDim.x + threadIdx.x;
  if (i >= N) return;
  unsigned k = key[i];
  inv[i] = rank[k];
  unsigned posn = atomicAdd(&ptCursor[k], 1u);
  ptOrder[posn] = (unsigned)i;
}

// ---- one wave per voxel: feature max (lane=feature, coalesced row reads) + pos mean ----
__global__ void __launch_bounds__(256) k_pool(const float* __restrict__ x,
                                              const float* __restrict__ pos,
                                              const unsigned* __restrict__ ptOrder,
                                              const unsigned* __restrict__ ptStart,
                                              const unsigned* __restrict__ cnt,
                                              const unsigned* __restrict__ ukeyArr,
                                              const unsigned* __restrict__ hdr,
                                              float* __restrict__ out) {
  unsigned gtid = blockIdx.x * blockDim.x + threadIdx.x;
  unsigned m = gtid >> 6;
  unsigned lane = gtid & 63u;
  unsigned M = hdr[3];
  if (m >= M) return;
  unsigned k = ukeyArr[m];
  unsigned start = ptStart[k];
  unsigned n = cnt[k];
  float acc = -__builtin_huge_valf();
  float psum = 0.0f;
  for (unsigned j = 0; j < n; ++j) {
    unsigned p = ptOrder[start + j];
    acc = fmaxf(acc, x[p * 64u + lane]);
    if (lane < 3) psum += pos[3u * p + lane];
  }
  out[(unsigned long long)m * 64u + lane] = acc;
  if (lane < 3) {
    unsigned long long O1 = 64ull * M;
    out[O1 + 3ull * m + lane] = psum / (float)n;
  }
}

// ---- edges: partition histogram (LDS-aggregated) ----
__global__ void __launch_bounds__(256) k_ehist2(const int2* __restrict__ ei,
                                                const unsigned* __restrict__ inv,
                                                unsigned* __restrict__ partCnt, int E, int span) {
  __shared__ unsigned h[NPART];
  for (int i = threadIdx.x; i < NPART; i += 256) h[i] = 0;
  __syncthreads();
  int lo = blockIdx.x * span;
  int hi = min(E, lo + span);
  for (int e = lo + threadIdx.x; e < hi; e += 256) {
    int2 pr = ei[e];
    unsigned a = inv[pr.x], b = inv[pr.y];
    if (a != b) atomicAdd(&h[a >> 9], 1u);
  }
  __syncthreads();
  for (int i = threadIdx.x; i < NPART; i += 256) {
    unsigned v = h[i];
    if (v) atomicAdd(&partCnt[i], v);
  }
}

// ---- edges: partition scatter (block-reserved contiguous runs) ----
__global__ void __launch_bounds__(256) k_pscatter(const int2* __restrict__ ei,
                                                  const unsigned* __restrict__ inv,
                                                  unsigned* __restrict__ partCursor,
                                                  unsigned long long* __restrict__ pStage,
                                                  int E, int span) {
  __shared__ unsigned h[NPART];
  for (int i = threadIdx.x; i < NPART; i += 256) h[i] = 0;
  __syncthreads();
  int lo = blockIdx.x * span;
  int hi = min(E, lo + span);
  for (int e = lo + threadIdx.x; e < hi; e += 256) {
    int2 pr = ei[e];
    unsigned a = inv[pr.x], b = inv[pr.y];
    if (a != b) atomicAdd(&h[a >> 9], 1u);
  }
  __syncthreads();
  for (int i = threadIdx.x; i < NPART; i += 256) {
    unsigned v = h[i];
    h[i] = v ? atomicAdd(&partCursor[i], v) : 0u;
  }
  __syncthreads();
  for (int e = lo + threadIdx.x; e < hi; e += 256) {
    int2 pr = ei[e];
    unsigned a = inv[pr.x], b = inv[pr.y];
    if (a != b) {
      unsigned off = atomicAdd(&h[a >> 9], 1u);
      pStage[off] = ((unsigned long long)a << 19) | b;
    }
  }
}

// ---- per-partition: LDS counting-sort by srcLow, element-parallel rank-sort by dst,
//      global dedup flag + block-scan compaction ----
// code28 = (srcLow<<19)|dst; full 38-bit code = ((u64)p<<28)|code28.
__global__ void __launch_bounds__(256) k_bucket(unsigned long long* __restrict__ pStage,
                                                const unsigned* __restrict__ partStart,
                                                unsigned* __restrict__ partDistinct) {
  __shared__ unsigned dstL[SCAP2];
  __shared__ unsigned h[PB];
  __shared__ unsigned bbase[PB + 1];
  __shared__ unsigned stmp[256];
  unsigned p = blockIdx.x;
  unsigned s = partStart[p];
  unsigned c = partStart[p + 1] - s;
  unsigned t = threadIdx.x;
  for (int i = t; i < PB; i += 256) h[i] = 0;
  __syncthreads();
  if (c <= SCAP2) {
    // low dword of each 8B code holds all 28 relevant bits (little-endian)
    const unsigned* lo32 = (const unsigned*)(pStage + s);
    // 1) histogram by srcLow
    for (unsigned i = t; i < c; i += 256) {
      unsigned code28 = lo32[2 * i] & 0x0FFFFFFFu;
      atomicAdd(&h[code28 >> 19], 1u);
    }
    __syncthreads();
    {  // 2) exclusive scan h -> bbase
      unsigned a = h[2 * t], b = h[2 * t + 1], sum = a + b;
      stmp[t] = sum;
      __syncthreads();
      for (int off = 1; off < 256; off <<= 1) {
        unsigned x = (t >= (unsigned)off) ? stmp[t - off] : 0u;
        __syncthreads(); stmp[t] += x; __syncthreads();
      }
      unsigned excl = stmp[t] - sum;
      bbase[2 * t] = excl; bbase[2 * t + 1] = excl + a;
      if (t == 255) bbase[PB] = stmp[255];
    }
    __syncthreads();
    for (int i = t; i < PB; i += 256) h[i] = bbase[i];  // h becomes cursor
    __syncthreads();
    // 3) scatter code28 into bucket-contiguous LDS
    for (unsigned i = t; i < c; i += 256) {
      unsigned code28 = lo32[2 * i] & 0x0FFFFFFFu;
      unsigned off = atomicAdd(&h[code28 >> 19], 1u);
      dstL[off] = code28;
    }
    __syncthreads();
    // 4) element-parallel stable rank within bucket (independent, pipelined LDS reads)
    unsigned L = (c + 255) >> 8;  // elements per thread (blocked), <= 32
    unsigned vv[32], rr[32];
#pragma unroll
    for (unsigned k = 0; k < 32; ++k) {
      unsigned i = t * L + k;
      if (k < L && i < c) {
        unsigned v = dstL[i];
        unsigned b = v >> 19;
        unsigned blo = bbase[b], bhi = bbase[b + 1];
        unsigned r = blo;
        for (unsigned j = blo; j < bhi; ++j) {
          unsigned u = dstL[j];
          r += (u < v) || (u == v && j < i);
        }
        vv[k] = v; rr[k] = r;
      }
    }
    __syncthreads();
    // 5) in-place scatter to sorted position
#pragma unroll
    for (unsigned k = 0; k < 32; ++k) {
      unsigned i = t * L + k;
      if (k < L && i < c) dstL[rr[k]] = vv[k];
    }
    __syncthreads();
    // 6) dedup flags (whole partition is now sorted by code28) + block scan
    unsigned flm = 0, localSum = 0;
#pragma unroll
    for (unsigned k = 0; k < 32; ++k) {
      unsigned i = t * L + k;
      if (k < L && i < c) {
        unsigned v = dstL[i];
        unsigned pv = dstL[i - (i > 0 ? 1u : 0u)];
        unsigned f = (i == 0) | (pv != v);
        flm |= f << k;
        localSum += f;
      }
    }
    stmp[t] = localSum;
    __syncthreads();
    for (int off = 1; off < 256; off <<= 1) {
      unsigned x = (t >= (unsigned)off) ? stmp[t - off] : 0u;
      __syncthreads(); stmp[t] += x; __syncthreads();
    }
    unsigned pos = stmp[t] - localSum;
    unsigned long long pbase = (unsigned long long)p << 28;
    // 7) compact distinct codes back to pStage (sorted by (src,dst))
#pragma unroll
    for (unsigned k = 0; k < 32; ++k) {
      unsigned i = t * L + k;
      if (k < L && i < c && ((flm >> k) & 1u)) {
        pStage[s + pos] = pbase | (unsigned long long)dstL[i];
        ++pos;
      }
    }
    if (t == 255) partDistinct[p] = stmp[255];
  } else if (t == 0) {  // fallback, statistically unreachable (mean+24sigma)
    for (unsigned i = 1; i < c; ++i) {
      unsigned long long v = pStage[s + i];
      long long j = (long long)i - 1;
      while (j >= 0 && pStage[s + j] > v) { pStage[s + j + 1] = pStage[s + j]; --j; }
      pStage[s + j + 1] = v;
    }
    unsigned d = 0;
    unsigned long long prev = ~0ull;
    for (unsigned i = 0; i < c; ++i) {
      unsigned long long v = pStage[s + i];
      if (i == 0 || v != prev) { pStage[s + d] = v; ++d; }
      prev = v;
    }
    partDistinct[p] = d;
  }
}

// ---- write deduped edges ----
__global__ void __launch_bounds__(256) k_ewriteP(const unsigned long long* __restrict__ pStage,
                                                 const unsigned* __restrict__ partStart,
                                                 const unsigned* __restrict__ partOut,
                                                 const unsigned* __restrict__ hdr,
                                                 float* __restrict__ out) {
  unsigned p = blockIdx.x;
  unsigned s = partStart[p];
  unsigned rbase = partOut[p];
  unsigned d = partOut[p + 1] - rbase;
  unsigned M = hdr[3];
  unsigned long long O2 = 67ull * M;
  for (unsigned j = threadIdx.x; j < d; j += 256) {
    unsigned long long code = pStage[s + j];
    unsigned long long row = (unsigned long long)rbase + j;
    out[O2 + 2 * row + 0] = (float)(unsigned)(code >> 19);
    out[O2 + 2 * row + 1] = (float)(unsigned)(code & 0x7FFFFu);
  }
}

// ---- self loops + new_batch ----
__global__ void k_final(const unsigned* __restrict__ ukeyArr, const unsigned* __restrict__ hdr,
                        float* __restrict__ out) {
  unsigned m = blockIdx.x * blockDim.x + threadIdx.x;
  unsigned M = hdr[3];
  if (m >= M) return;
  unsigned Ed = hdr[5];
  unsigned long long O2 = 67ull * M;
  unsigned long long row = (unsigned long long)Ed + m;
  float fm = (float)m;
  out[O2 + 2 * row + 0] = fm;
  out[O2 + 2 * row + 1] = fm;
  unsigned s0 = hdr[0] + 1, s1 = hdr[1] + 1, s2 = hdr[2] + 1;
  unsigned vol = s0 * s1 * s2;
  unsigned long long O3 = O2 + 2ull * (Ed + M);
  out[O3 + m] = (float)(ukeyArr[m] / vol);
}

extern "C" void kernel_launch(void* const* d_in, const int* in_sizes, int n_in,
                              void* d_out, int out_size, void* d_ws, size_t ws_size,
                              hipStream_t stream) {
  const float* x = (const float*)d_in[0];
  const float* pos = (const float*)d_in[1];
  const int* ei = (const int*)d_in[2];
  const int* batch = (const int*)d_in[3];
  float* out = (float*)d_out;
  int N = in_sizes[3];
  int E = in_sizes[2] / 2;

  unsigned* ws = (unsigned*)d_ws;
  // ws layout (u32 units)
  unsigned* hdr          = ws;                        // 64
  unsigned* cnt          = ws + 64;                   // KSP
  unsigned* partCnt      = cnt + KSP;                 // NPART
  unsigned* partDistinct = partCnt + NPART;           // NPART
  unsigned* rank         = partDistinct + NPART;      // KSP
  unsigned* ukeyArr      = rank + KSP;                // KSP
  unsigned* partStart    = ukeyArr + KSP;             // NPART+2
  unsigned* partCursor   = partStart + NPART + 2;     // NPART
  unsigned* partOut      = partCursor + NPART;        // NPART+2
  unsigned* chunkSums    = partOut + NPART + 2;       // 1024
  unsigned* key          = chunkSums + 1024;          // N
  unsigned* inv          = key + N;                   // N
  unsigned* pS32         = inv + ((N + 1) & ~1);      // 8B-aligned
  unsigned long long* pStage = (unsigned long long*)pS32;  // E u64
  // scratch aliased into pStage region (dead until k_pscatter; stream-ordered):
  unsigned* ptStart  = pS32;                  // KSP
  unsigned* ptCursor = pS32 + KSP;            // KSP
  unsigned* ptOrder  = pS32 + 2 * KSP;        // N   (2*KSP+N u32 = 5.8MB <= 2*E u32)

  // zero: hdr + cnt + partCnt + partDistinct (contiguous); all of d_out
  hipMemsetAsync(ws, 0, (size_t)(64 + KSP + 2 * NPART) * 4, stream);
  hipMemsetAsync(d_out, 0, (size_t)out_size * 4, stream);

  const int B = 256;
  int gN = (N + B - 1) / B;
  int gK = (KSP + B - 1) / B;
  int gP = (int)(((long long)N * 64 + B - 1) / B);  // k_pool: one wave per voxel, M<=N
  int span = (E + 255) / 256;  // edges per block for the 256-block edge passes

  k_qmax<<<gN, B, 0, stream>>>(pos, hdr, N);
  k_keys<<<gN, B, 0, stream>>>(pos, batch, hdr, key, cnt, N);

  // rank = exclusive scan of presence(cnt); total -> hdr[3] = M
  scanA<<<NCHUNK, SCAN_BLOCK, 0, stream>>>(cnt, rank, chunkSums, KSP, 1);
  scanB<<<1, 1024, 0, stream>>>(chunkSums, &hdr[3], NCHUNK);
  scanC<<<gK, B, 0, stream>>>(rank, nullptr, chunkSums, KSP);

  // ptStart = exclusive scan of counts; cursor copy for the scatter
  scanA<<<NCHUNK, SCAN_BLOCK, 0, stream>>>(cnt, ptStart, chunkSums, KSP, 0);
  scanB<<<1, 1024, 0, stream>>>(chunkSums, &hdr[6], NCHUNK);
  scanC<<<gK, B, 0, stream>>>(ptStart, ptCursor, chunkSums, KSP);

  k_ukey<<<gK, B, 0, stream>>>(cnt, rank, ukeyArr);
  k_scatter<<<gN, B, 0, stream>>>(key, rank, inv, ptCursor, ptOrder, N);
  k_pool<<<gP, B, 0, stream>>>(x, pos, ptOrder, ptStart, cnt, ukeyArr, hdr, out);

  // edges: partition -> LDS sort/dedup -> write
  const int2* ei2 = (const int2*)ei;
  k_ehist2<<<256, 256, 0, stream>>>(ei2, inv, partCnt, E, span);
  k_scan1024<<<1, NPART, 0, stream>>>(partCnt, partStart, partCursor, &hdr[4]);
  k_pscatter<<<256, 256, 0, stream>>>(ei2, inv, partCursor, pStage, E, span);
  k_bucket<<<NPART, 256, 0, stream>>>(pStage, partStart, partDistinct);
  k_scan1024<<<1, NPART, 0, stream>>>(partDistinct, partOut, nullptr, &hdr[5]);
  k_ewriteP<<<NPART, 256, 0, stream>>>(pStage, partStart, partOut, hdr, out);
  k_final<<<gK, B, 0, stream>>>(ukeyArr, hdr, out);

  (void)n_in; (void)ws_size;
}

// Round 3
// 525.538 us; speedup vs baseline: 1.2094x; 1.2094x over previous
//
#include <hip/hip_runtime.h>

// GraphPooling: voxel-grid pooling.
//  inputs: x[N,64] f32, pos[N,3] f32, edge_index[E,2] i32, batch[N] i32
//  outputs (concat, f32): pooled_x[M,64], pos_mean[M,3], ei_out[Ed+M,2], new_batch[M]
// Keyspace: key = ((b*s0+qx)*s1+qy)*s2+qz < 16*32*32*32 = 524288.
// Pooling: voxel-sorted point permutation (ptOrder) + compact segment starts
// (cStart[m], aliased onto dead ptCursor) + 8-lanes-per-voxel segment reduce:
// 8 independent voxels per wave (8x MLP), full 256B row per group via 2x float4.
// Edge pipeline: partition by src>>9 (1024 partitions, ~5.8k edges each),
// per-partition LDS counting-sort by srcLow + element-parallel rank-sort by dst,
// global (in-partition) dedup flag + block scan compaction.
// Codes packed as (src<<19)|dst (38 bits); in-LDS code28 = (srcLow<<19)|dst.

#define KSP 524288
#define SCAN_BLOCK 256
#define SCAN_ITEMS 16
#define SCAN_CHUNK 4096            // SCAN_BLOCK * SCAN_ITEMS
#define NCHUNK (KSP / SCAN_CHUNK)  // 128
#define NPART 1024
#define PB 512                     // voxel ranks per partition (KSP/NPART)
#define SCAP2 8192                 // LDS cap: edges per partition (mean ~5.8k, sigma ~150)

// ws header slots (u32): [0..2]=max qpos, [3]=M, [4]=validE, [5]=Ed, [6]=scratch total

// ---- per-point: max of quantized coords ----
__global__ void k_qmax(const float* __restrict__ pos, unsigned* hdr, int N) {
  __shared__ unsigned sm[3];
  if (threadIdx.x < 3) sm[threadIdx.x] = 0;
  __syncthreads();
  int i = blockIdx.x * blockDim.x + threadIdx.x;
  if (i < N) {
    int q0 = (int)floorf(pos[3 * i + 0] * 0.25f);
    int q1 = (int)floorf(pos[3 * i + 1] * 0.25f);
    int q2 = (int)floorf(pos[3 * i + 2] * 0.25f);
    atomicMax(&sm[0], (unsigned)q0);
    atomicMax(&sm[1], (unsigned)q1);
    atomicMax(&sm[2], (unsigned)q2);
  }
  __syncthreads();
  if (threadIdx.x < 3) atomicMax(&hdr[threadIdx.x], sm[threadIdx.x]);
}

// ---- per-point: voxel key + histogram ----
__global__ void k_keys(const float* __restrict__ pos, const int* __restrict__ batch,
                       const unsigned* __restrict__ hdr, unsigned* __restrict__ key,
                       unsigned* __restrict__ cnt, int N) {
  int i = blockIdx.x * blockDim.x + threadIdx.x;
  if (i >= N) return;
  unsigned s0 = hdr[0] + 1, s1 = hdr[1] + 1, s2 = hdr[2] + 1;
  unsigned q0 = (unsigned)(int)floorf(pos[3 * i + 0] * 0.25f);
  unsigned q1 = (unsigned)(int)floorf(pos[3 * i + 1] * 0.25f);
  unsigned q2 = (unsigned)(int)floorf(pos[3 * i + 2] * 0.25f);
  unsigned k = (((unsigned)batch[i] * s0 + q0) * s1 + q1) * s2 + q2;
  key[i] = k;
  atomicAdd(&cnt[k], 1u);
}

// ---- 3-phase exclusive scan over KSP ----
__global__ void scanA(const unsigned* __restrict__ in, unsigned* __restrict__ out,
                      unsigned* __restrict__ chunkSums, int n, int presence) {
  __shared__ unsigned lds[SCAN_BLOCK];
  int tbase = blockIdx.x * SCAN_CHUNK + threadIdx.x * SCAN_ITEMS;
  unsigned vals[SCAN_ITEMS];
  unsigned sum = 0;
  for (int i = 0; i < SCAN_ITEMS; ++i) {
    unsigned v = 0;
    int idx = tbase + i;
    if (idx < n) { v = in[idx]; if (presence) v = v ? 1u : 0u; }
    vals[i] = sum;
    sum += v;
  }
  lds[threadIdx.x] = sum;
  __syncthreads();
  for (int off = 1; off < SCAN_BLOCK; off <<= 1) {
    unsigned t = (threadIdx.x >= (unsigned)off) ? lds[threadIdx.x - off] : 0u;
    __syncthreads();
    lds[threadIdx.x] += t;
    __syncthreads();
  }
  unsigned threadExcl = lds[threadIdx.x] - sum;
  for (int i = 0; i < SCAN_ITEMS; ++i) {
    int idx = tbase + i;
    if (idx < n) out[idx] = threadExcl + vals[i];
  }
  if (threadIdx.x == SCAN_BLOCK - 1) chunkSums[blockIdx.x] = lds[SCAN_BLOCK - 1];
}

__global__ void scanB(unsigned* chunkSums, unsigned* totalDst, int nchunks) {
  __shared__ unsigned lds[1024];
  unsigned v = (threadIdx.x < (unsigned)nchunks) ? chunkSums[threadIdx.x] : 0u;
  lds[threadIdx.x] = v;
  __syncthreads();
  for (int off = 1; off < 1024; off <<= 1) {
    unsigned t = (threadIdx.x >= (unsigned)off) ? lds[threadIdx.x - off] : 0u;
    __syncthreads();
    lds[threadIdx.x] += t;
    __syncthreads();
  }
  if (threadIdx.x < (unsigned)nchunks) chunkSums[threadIdx.x] = lds[threadIdx.x] - v;
  if (threadIdx.x == 0 && totalDst) *totalDst = lds[1023];
}

__global__ void scanC(unsigned* __restrict__ out, unsigned* __restrict__ out2,
                      const unsigned* __restrict__ chunkSums, int n) {
  int idx = blockIdx.x * blockDim.x + threadIdx.x;
  if (idx >= n) return;
  unsigned v = out[idx] + chunkSums[idx / SCAN_CHUNK];
  out[idx] = v;
  if (out2) out2[idx] = v;
}

// ---- single-block exclusive scan of NPART entries ----
__global__ void k_scan1024(const unsigned* __restrict__ in, unsigned* __restrict__ outStart,
                           unsigned* __restrict__ outCursor, unsigned* __restrict__ totalDst) {
  __shared__ unsigned lds[NPART];
  unsigned t = threadIdx.x;
  unsigned v = in[t];
  lds[t] = v;
  __syncthreads();
  for (int off = 1; off < NPART; off <<= 1) {
    unsigned x = (t >= (unsigned)off) ? lds[t - off] : 0u;
    __syncthreads();
    lds[t] += x;
    __syncthreads();
  }
  unsigned excl = lds[t] - v;
  outStart[t] = excl;
  if (outCursor) outCursor[t] = excl;
  if (t == NPART - 1) {
    outStart[NPART] = lds[t];
    if (totalDst) *totalDst = lds[t];
  }
}

// ---- build rank -> key map ----
__global__ void k_ukey(const unsigned* __restrict__ cnt, const unsigned* __restrict__ rank,
                       unsigned* __restrict__ ukeyArr) {
  int k = blockIdx.x * blockDim.x + threadIdx.x;
  if (k >= KSP) return;
  if (cnt[k]) ukeyArr[rank[k]] = (unsigned)k;
}

// ---- per-point: inv index + voxel-sorted permutation ----
__global__ void k_scatter(const unsigned* __restrict__ key, const unsigned* __restrict__ rank,
                          unsigned* __restrict__ inv, unsigned* __restrict__ ptCursor,
                          unsigned* __restrict__ ptOrder, int N) {
  int i = blockIdx.x * blockDim.x + threadIdx.x;
  if (i >= N) return;
  unsigned k = key[i];
  inv[i] = rank[k];
  unsigned posn = atomicAdd(&ptCursor[k], 1u);
  ptOrder[posn] = (unsigned)i;
}

// ---- compact per-rank segment starts (runs after k_scatter; cStart aliases ptCursor) ----
__global__ void k_cstart(const unsigned* __restrict__ cnt, const unsigned* __restrict__ rank,
                         const unsigned* __restrict__ ptStart, const unsigned* __restrict__ hdr,
                         unsigned* __restrict__ cStart, int N) {
  int k = blockIdx.x * blockDim.x + threadIdx.x;
  if (k >= KSP) return;
  if (cnt[k]) cStart[rank[k]] = ptStart[k];
  if (k == 0) cStart[hdr[3]] = (unsigned)N;
}

// ---- 8 lanes per voxel: feature max (2x float4 per lane = full 256B row) + pos mean.
//      8 independent voxels per wave -> 8 concurrent dependent-chains (latency hiding). ----
__global__ void __launch_bounds__(256) k_pool(const float4* __restrict__ x4,
                                              const float* __restrict__ pos,
                                              const unsigned* __restrict__ ptOrder,
                                              const unsigned* __restrict__ cStart,
                                              const unsigned* __restrict__ hdr,
                                              float* __restrict__ out) {
  unsigned gtid = blockIdx.x * blockDim.x + threadIdx.x;
  unsigned m = gtid >> 3;     // voxel id
  unsigned l = gtid & 7u;     // lane-in-group, covers features [l*4..l*4+3] and [(8+l)*4..]
  unsigned M = hdr[3];
  if (m >= M) return;
  unsigned start = cStart[m];
  unsigned n = cStart[m + 1] - start;
  const float NI = -__builtin_huge_valf();
  float4 a0 = make_float4(NI, NI, NI, NI);
  float4 a1 = a0;
  float psum = 0.0f;
  for (unsigned j = 0; j < n; ++j) {
    unsigned p = ptOrder[start + j];
    float4 v0 = x4[p * 16u + l];
    float4 v1 = x4[p * 16u + 8u + l];
    a0.x = fmaxf(a0.x, v0.x); a0.y = fmaxf(a0.y, v0.y);
    a0.z = fmaxf(a0.z, v0.z); a0.w = fmaxf(a0.w, v0.w);
    a1.x = fmaxf(a1.x, v1.x); a1.y = fmaxf(a1.y, v1.y);
    a1.z = fmaxf(a1.z, v1.z); a1.w = fmaxf(a1.w, v1.w);
    if (l < 3) psum += pos[3u * p + l];
  }
  float4* o4 = (float4*)out;
  o4[m * 16u + l] = a0;
  o4[m * 16u + 8u + l] = a1;
  if (l < 3) {
    unsigned long long O1 = 64ull * M;
    out[O1 + 3ull * m + l] = psum / (float)n;
  }
}

// ---- edges: partition histogram (LDS-aggregated) ----
__global__ void __launch_bounds__(256) k_ehist2(const int2* __restrict__ ei,
                                                const unsigned* __restrict__ inv,
                                                unsigned* __restrict__ partCnt, int E, int span) {
  __shared__ unsigned h[NPART];
  for (int i = threadIdx.x; i < NPART; i += 256) h[i] = 0;
  __syncthreads();
  int lo = blockIdx.x * span;
  int hi = min(E, lo + span);
  for (int e = lo + threadIdx.x; e < hi; e += 256) {
    int2 pr = ei[e];
    unsigned a = inv[pr.x], b = inv[pr.y];
    if (a != b) atomicAdd(&h[a >> 9], 1u);
  }
  __syncthreads();
  for (int i = threadIdx.x; i < NPART; i += 256) {
    unsigned v = h[i];
    if (v) atomicAdd(&partCnt[i], v);
  }
}

// ---- edges: partition scatter (block-reserved contiguous runs) ----
__global__ void __launch_bounds__(256) k_pscatter(const int2* __restrict__ ei,
                                                  const unsigned* __restrict__ inv,
                                                  unsigned* __restrict__ partCursor,
                                                  unsigned long long* __restrict__ pStage,
                                                  int E, int span) {
  __shared__ unsigned h[NPART];
  for (int i = threadIdx.x; i < NPART; i += 256) h[i] = 0;
  __syncthreads();
  int lo = blockIdx.x * span;
  int hi = min(E, lo + span);
  for (int e = lo + threadIdx.x; e < hi; e += 256) {
    int2 pr = ei[e];
    unsigned a = inv[pr.x], b = inv[pr.y];
    if (a != b) atomicAdd(&h[a >> 9], 1u);
  }
  __syncthreads();
  for (int i = threadIdx.x; i < NPART; i += 256) {
    unsigned v = h[i];
    h[i] = v ? atomicAdd(&partCursor[i], v) : 0u;
  }
  __syncthreads();
  for (int e = lo + threadIdx.x; e < hi; e += 256) {
    int2 pr = ei[e];
    unsigned a = inv[pr.x], b = inv[pr.y];
    if (a != b) {
      unsigned off = atomicAdd(&h[a >> 9], 1u);
      pStage[off] = ((unsigned long long)a << 19) | b;
    }
  }
}

// ---- per-partition: LDS counting-sort by srcLow, element-parallel rank-sort by dst,
//      global dedup flag + block-scan compaction ----
// code28 = (srcLow<<19)|dst; full 38-bit code = ((u64)p<<28)|code28.
__global__ void __launch_bounds__(256) k_bucket(unsigned long long* __restrict__ pStage,
                                                const unsigned* __restrict__ partStart,
                                                unsigned* __restrict__ partDistinct) {
  __shared__ unsigned dstL[SCAP2];
  __shared__ unsigned h[PB];
  __shared__ unsigned bbase[PB + 1];
  __shared__ unsigned stmp[256];
  unsigned p = blockIdx.x;
  unsigned s = partStart[p];
  unsigned c = partStart[p + 1] - s;
  unsigned t = threadIdx.x;
  for (int i = t; i < PB; i += 256) h[i] = 0;
  __syncthreads();
  if (c <= SCAP2) {
    // low dword of each 8B code holds all 28 relevant bits (little-endian)
    const unsigned* lo32 = (const unsigned*)(pStage + s);
    // 1) histogram by srcLow
    for (unsigned i = t; i < c; i += 256) {
      unsigned code28 = lo32[2 * i] & 0x0FFFFFFFu;
      atomicAdd(&h[code28 >> 19], 1u);
    }
    __syncthreads();
    {  // 2) exclusive scan h -> bbase
      unsigned a = h[2 * t], b = h[2 * t + 1], sum = a + b;
      stmp[t] = sum;
      __syncthreads();
      for (int off = 1; off < 256; off <<= 1) {
        unsigned x = (t >= (unsigned)off) ? stmp[t - off] : 0u;
        __syncthreads(); stmp[t] += x; __syncthreads();
      }
      unsigned excl = stmp[t] - sum;
      bbase[2 * t] = excl; bbase[2 * t + 1] = excl + a;
      if (t == 255) bbase[PB] = stmp[255];
    }
    __syncthreads();
    for (int i = t; i < PB; i += 256) h[i] = bbase[i];  // h becomes cursor
    __syncthreads();
    // 3) scatter code28 into bucket-contiguous LDS
    for (unsigned i = t; i < c; i += 256) {
      unsigned code28 = lo32[2 * i] & 0x0FFFFFFFu;
      unsigned off = atomicAdd(&h[code28 >> 19], 1u);
      dstL[off] = code28;
    }
    __syncthreads();
    // 4) element-parallel stable rank within bucket (independent, pipelined LDS reads)
    unsigned L = (c + 255) >> 8;  // elements per thread (blocked), <= 32
    unsigned vv[32], rr[32];
#pragma unroll
    for (unsigned k = 0; k < 32; ++k) {
      unsigned i = t * L + k;
      if (k < L && i < c) {
        unsigned v = dstL[i];
        unsigned b = v >> 19;
        unsigned blo = bbase[b], bhi = bbase[b + 1];
        unsigned r = blo;
        for (unsigned j = blo; j < bhi; ++j) {
          unsigned u = dstL[j];
          r += (u < v) || (u == v && j < i);
        }
        vv[k] = v; rr[k] = r;
      }
    }
    __syncthreads();
    // 5) in-place scatter to sorted position
#pragma unroll
    for (unsigned k = 0; k < 32; ++k) {
      unsigned i = t * L + k;
      if (k < L && i < c) dstL[rr[k]] = vv[k];
    }
    __syncthreads();
    // 6) dedup flags (whole partition is now sorted by code28) + block scan
    unsigned flm = 0, localSum = 0;
#pragma unroll
    for (unsigned k = 0; k < 32; ++k) {
      unsigned i = t * L + k;
      if (k < L && i < c) {
        unsigned v = dstL[i];
        unsigned pv = dstL[i - (i > 0 ? 1u : 0u)];
        unsigned f = (i == 0) | (pv != v);
        flm |= f << k;
        localSum += f;
      }
    }
    stmp[t] = localSum;
    __syncthreads();
    for (int off = 1; off < 256; off <<= 1) {
      unsigned x = (t >= (unsigned)off) ? stmp[t - off] : 0u;
      __syncthreads(); stmp[t] += x; __syncthreads();
    }
    unsigned pos = stmp[t] - localSum;
    unsigned long long pbase = (unsigned long long)p << 28;
    // 7) compact distinct codes back to pStage (sorted by (src,dst))
#pragma unroll
    for (unsigned k = 0; k < 32; ++k) {
      unsigned i = t * L + k;
      if (k < L && i < c && ((flm >> k) & 1u)) {
        pStage[s + pos] = pbase | (unsigned long long)dstL[i];
        ++pos;
      }
    }
    if (t == 255) partDistinct[p] = stmp[255];
  } else if (t == 0) {  // fallback, statistically unreachable (mean+24sigma)
    for (unsigned i = 1; i < c; ++i) {
      unsigned long long v = pStage[s + i];
      long long j = (long long)i - 1;
      while (j >= 0 && pStage[s + j] > v) { pStage[s + j + 1] = pStage[s + j]; --j; }
      pStage[s + j + 1] = v;
    }
    unsigned d = 0;
    unsigned long long prev = ~0ull;
    for (unsigned i = 0; i < c; ++i) {
      unsigned long long v = pStage[s + i];
      if (i == 0 || v != prev) { pStage[s + d] = v; ++d; }
      prev = v;
    }
    partDistinct[p] = d;
  }
}

// ---- write deduped edges ----
__global__ void __launch_bounds__(256) k_ewriteP(const unsigned long long* __restrict__ pStage,
                                                 const unsigned* __restrict__ partStart,
                                                 const unsigned* __restrict__ partOut,
                                                 const unsigned* __restrict__ hdr,
                                                 float* __restrict__ out) {
  unsigned p = blockIdx.x;
  unsigned s = partStart[p];
  unsigned rbase = partOut[p];
  unsigned d = partOut[p + 1] - rbase;
  unsigned M = hdr[3];
  unsigned long long O2 = 67ull * M;
  for (unsigned j = threadIdx.x; j < d; j += 256) {
    unsigned long long code = pStage[s + j];
    unsigned long long row = (unsigned long long)rbase + j;
    out[O2 + 2 * row + 0] = (float)(unsigned)(code >> 19);
    out[O2 + 2 * row + 1] = (float)(unsigned)(code & 0x7FFFFu);
  }
}

// ---- self loops + new_batch ----
__global__ void k_final(const unsigned* __restrict__ ukeyArr, const unsigned* __restrict__ hdr,
                        float* __restrict__ out) {
  unsigned m = blockIdx.x * blockDim.x + threadIdx.x;
  unsigned M = hdr[3];
  if (m >= M) return;
  unsigned Ed = hdr[5];
  unsigned long long O2 = 67ull * M;
  unsigned long long row = (unsigned long long)Ed + m;
  float fm = (float)m;
  out[O2 + 2 * row + 0] = fm;
  out[O2 + 2 * row + 1] = fm;
  unsigned s0 = hdr[0] + 1, s1 = hdr[1] + 1, s2 = hdr[2] + 1;
  unsigned vol = s0 * s1 * s2;
  unsigned long long O3 = O2 + 2ull * (Ed + M);
  out[O3 + m] = (float)(ukeyArr[m] / vol);
}

extern "C" void kernel_launch(void* const* d_in, const int* in_sizes, int n_in,
                              void* d_out, int out_size, void* d_ws, size_t ws_size,
                              hipStream_t stream) {
  const float* x = (const float*)d_in[0];
  const float* pos = (const float*)d_in[1];
  const int* ei = (const int*)d_in[2];
  const int* batch = (const int*)d_in[3];
  float* out = (float*)d_out;
  int N = in_sizes[3];
  int E = in_sizes[2] / 2;

  unsigned* ws = (unsigned*)d_ws;
  // ws layout (u32 units)
  unsigned* hdr          = ws;                        // 64
  unsigned* cnt          = ws + 64;                   // KSP
  unsigned* partCnt      = cnt + KSP;                 // NPART
  unsigned* partDistinct = partCnt + NPART;           // NPART
  unsigned* rank         = partDistinct + NPART;      // KSP
  unsigned* ukeyArr      = rank + KSP;                // KSP
  unsigned* partStart    = ukeyArr + KSP;             // NPART+2
  unsigned* partCursor   = partStart + NPART + 2;     // NPART
  unsigned* partOut      = partCursor + NPART;        // NPART+2
  unsigned* chunkSums    = partOut + NPART + 2;       // 1024
  unsigned* key          = chunkSums + 1024;          // N
  unsigned* inv          = key + N;                   // N
  unsigned* pS32         = inv + ((N + 1) & ~1);      // 8B-aligned
  unsigned long long* pStage = (unsigned long long*)pS32;  // E u64
  // scratch aliased into pStage region (dead until k_pscatter; stream-ordered):
  unsigned* ptStart  = pS32;                  // KSP
  unsigned* ptCursor = pS32 + KSP;            // KSP (becomes cStart after k_scatter)
  unsigned* ptOrder  = pS32 + 2 * KSP;        // N   (2*KSP+N u32 = 5.8MB <= 2*E u32)
  unsigned* cStart   = ptCursor;              // M+1 <= KSP, built by k_cstart

  // zero: hdr + cnt + partCnt + partDistinct (contiguous).
  // d_out needs no zero-fill: every output byte is written (pooled_x+pos_mean by
  // k_pool, edges by k_ewriteP, loops+new_batch by k_final).
  hipMemsetAsync(ws, 0, (size_t)(64 + KSP + 2 * NPART) * 4, stream);

  const int B = 256;
  int gN = (N + B - 1) / B;
  int gK = (KSP + B - 1) / B;
  int gP = (int)(((long long)N * 8 + B - 1) / B);  // k_pool: 8 lanes per voxel, M<=N
  int span = (E + 255) / 256;  // edges per block for the 256-block edge passes

  k_qmax<<<gN, B, 0, stream>>>(pos, hdr, N);
  k_keys<<<gN, B, 0, stream>>>(pos, batch, hdr, key, cnt, N);

  // rank = exclusive scan of presence(cnt); total -> hdr[3] = M
  scanA<<<NCHUNK, SCAN_BLOCK, 0, stream>>>(cnt, rank, chunkSums, KSP, 1);
  scanB<<<1, 1024, 0, stream>>>(chunkSums, &hdr[3], NCHUNK);
  scanC<<<gK, B, 0, stream>>>(rank, nullptr, chunkSums, KSP);

  // ptStart = exclusive scan of counts; cursor copy for the scatter
  scanA<<<NCHUNK, SCAN_BLOCK, 0, stream>>>(cnt, ptStart, chunkSums, KSP, 0);
  scanB<<<1, 1024, 0, stream>>>(chunkSums, &hdr[6], NCHUNK);
  scanC<<<gK, B, 0, stream>>>(ptStart, ptCursor, chunkSums, KSP);

  k_ukey<<<gK, B, 0, stream>>>(cnt, rank, ukeyArr);
  k_scatter<<<gN, B, 0, stream>>>(key, rank, inv, ptCursor, ptOrder, N);
  k_cstart<<<gK, B, 0, stream>>>(cnt, rank, ptStart, hdr, cStart, N);
  k_pool<<<gP, B, 0, stream>>>((const float4*)x, pos, ptOrder, cStart, hdr, out);

  // edges: partition -> LDS sort/dedup -> write
  const int2* ei2 = (const int2*)ei;
  k_ehist2<<<256, 256, 0, stream>>>(ei2, inv, partCnt, E, span);
  k_scan1024<<<1, NPART, 0, stream>>>(partCnt, partStart, partCursor, &hdr[4]);
  k_pscatter<<<256, 256, 0, stream>>>(ei2, inv, partCursor, pStage, E, span);
  k_bucket<<<NPART, 256, 0, stream>>>(pStage, partStart, partDistinct);
  k_scan1024<<<1, NPART, 0, stream>>>(partDistinct, partOut, nullptr, &hdr[5]);
  k_ewriteP<<<NPART, 256, 0, stream>>>(pStage, partStart, partOut, hdr, out);
  k_final<<<gK, B, 0, stream>>>(ukeyArr, hdr, out);

  (void)n_in; (void)ws_size;
}

// Round 4
// 520.820 us; speedup vs baseline: 1.2204x; 1.0091x over previous
//
#include <hip/hip_runtime.h>

// GraphPooling: voxel-grid pooling.
//  inputs: x[N,64] f32, pos[N,3] f32, edge_index[E,2] i32, batch[N] i32
//  outputs (concat, f32): pooled_x[M,64], pos_mean[M,3], ei_out[Ed+M,2], new_batch[M]
// Keyspace: key = ((b*s0+qx)*s1+qy)*s2+qz < 16*32*32*32 = 524288.
// Pooling: voxel-sorted point permutation (ptOrder) + compact segment starts
// (cStart[m], aliased onto dead ptCursor) + 8-lanes-per-voxel segment reduce.
// Edge pipeline: partition by src>>9 (1024 partitions). pStage holds u32 code28 =
// (srcLow9<<19)|dst — partition id supplies the high bits. k_pscatter register-caches
// its codes between histogram and write loops (single read of ei/inv).
// k_bucket: LDS counting-sort by srcLow + element-parallel rank-sort by dst,
// global (in-partition) dedup flag + block scan compaction.

#define KSP 524288
#define SCAN_BLOCK 256
#define SCAN_ITEMS 16
#define SCAN_CHUNK 4096            // SCAN_BLOCK * SCAN_ITEMS
#define NCHUNK (KSP / SCAN_CHUNK)  // 128
#define NPART 1024
#define PB 512                     // voxel ranks per partition (KSP/NPART)
#define SCAP2 8192                 // LDS cap: edges per partition (mean ~5.8k, sigma ~150)
#define PS_ITERS 16                // edges per thread in k_pscatter (span = 256*PS_ITERS)

// ws header slots (u32): [0..2]=max qpos, [3]=M, [4]=validE, [5]=Ed, [6]=scratch total

// ---- per-point: max of quantized coords ----
__global__ void k_qmax(const float* __restrict__ pos, unsigned* hdr, int N) {
  __shared__ unsigned sm[3];
  if (threadIdx.x < 3) sm[threadIdx.x] = 0;
  __syncthreads();
  int i = blockIdx.x * blockDim.x + threadIdx.x;
  if (i < N) {
    int q0 = (int)floorf(pos[3 * i + 0] * 0.25f);
    int q1 = (int)floorf(pos[3 * i + 1] * 0.25f);
    int q2 = (int)floorf(pos[3 * i + 2] * 0.25f);
    atomicMax(&sm[0], (unsigned)q0);
    atomicMax(&sm[1], (unsigned)q1);
    atomicMax(&sm[2], (unsigned)q2);
  }
  __syncthreads();
  if (threadIdx.x < 3) atomicMax(&hdr[threadIdx.x], sm[threadIdx.x]);
}

// ---- per-point: voxel key + histogram ----
__global__ void k_keys(const float* __restrict__ pos, const int* __restrict__ batch,
                       const unsigned* __restrict__ hdr, unsigned* __restrict__ key,
                       unsigned* __restrict__ cnt, int N) {
  int i = blockIdx.x * blockDim.x + threadIdx.x;
  if (i >= N) return;
  unsigned s0 = hdr[0] + 1, s1 = hdr[1] + 1, s2 = hdr[2] + 1;
  unsigned q0 = (unsigned)(int)floorf(pos[3 * i + 0] * 0.25f);
  unsigned q1 = (unsigned)(int)floorf(pos[3 * i + 1] * 0.25f);
  unsigned q2 = (unsigned)(int)floorf(pos[3 * i + 2] * 0.25f);
  unsigned k = (((unsigned)batch[i] * s0 + q0) * s1 + q1) * s2 + q2;
  key[i] = k;
  atomicAdd(&cnt[k], 1u);
}

// ---- 3-phase exclusive scan over KSP ----
__global__ void scanA(const unsigned* __restrict__ in, unsigned* __restrict__ out,
                      unsigned* __restrict__ chunkSums, int n, int presence) {
  __shared__ unsigned lds[SCAN_BLOCK];
  int tbase = blockIdx.x * SCAN_CHUNK + threadIdx.x * SCAN_ITEMS;
  unsigned vals[SCAN_ITEMS];
  unsigned sum = 0;
  for (int i = 0; i < SCAN_ITEMS; ++i) {
    unsigned v = 0;
    int idx = tbase + i;
    if (idx < n) { v = in[idx]; if (presence) v = v ? 1u : 0u; }
    vals[i] = sum;
    sum += v;
  }
  lds[threadIdx.x] = sum;
  __syncthreads();
  for (int off = 1; off < SCAN_BLOCK; off <<= 1) {
    unsigned t = (threadIdx.x >= (unsigned)off) ? lds[threadIdx.x - off] : 0u;
    __syncthreads();
    lds[threadIdx.x] += t;
    __syncthreads();
  }
  unsigned threadExcl = lds[threadIdx.x] - sum;
  for (int i = 0; i < SCAN_ITEMS; ++i) {
    int idx = tbase + i;
    if (idx < n) out[idx] = threadExcl + vals[i];
  }
  if (threadIdx.x == SCAN_BLOCK - 1) chunkSums[blockIdx.x] = lds[SCAN_BLOCK - 1];
}

__global__ void scanB(unsigned* chunkSums, unsigned* totalDst, int nchunks) {
  __shared__ unsigned lds[1024];
  unsigned v = (threadIdx.x < (unsigned)nchunks) ? chunkSums[threadIdx.x] : 0u;
  lds[threadIdx.x] = v;
  __syncthreads();
  for (int off = 1; off < 1024; off <<= 1) {
    unsigned t = (threadIdx.x >= (unsigned)off) ? lds[threadIdx.x - off] : 0u;
    __syncthreads();
    lds[threadIdx.x] += t;
    __syncthreads();
  }
  if (threadIdx.x < (unsigned)nchunks) chunkSums[threadIdx.x] = lds[threadIdx.x] - v;
  if (threadIdx.x == 0 && totalDst) *totalDst = lds[1023];
}

__global__ void scanC(unsigned* __restrict__ out, unsigned* __restrict__ out2,
                      const unsigned* __restrict__ chunkSums, int n) {
  int idx = blockIdx.x * blockDim.x + threadIdx.x;
  if (idx >= n) return;
  unsigned v = out[idx] + chunkSums[idx / SCAN_CHUNK];
  out[idx] = v;
  if (out2) out2[idx] = v;
}

// ---- single-block exclusive scan of NPART entries ----
__global__ void k_scan1024(const unsigned* __restrict__ in, unsigned* __restrict__ outStart,
                           unsigned* __restrict__ outCursor, unsigned* __restrict__ totalDst) {
  __shared__ unsigned lds[NPART];
  unsigned t = threadIdx.x;
  unsigned v = in[t];
  lds[t] = v;
  __syncthreads();
  for (int off = 1; off < NPART; off <<= 1) {
    unsigned x = (t >= (unsigned)off) ? lds[t - off] : 0u;
    __syncthreads();
    lds[t] += x;
    __syncthreads();
  }
  unsigned excl = lds[t] - v;
  outStart[t] = excl;
  if (outCursor) outCursor[t] = excl;
  if (t == NPART - 1) {
    outStart[NPART] = lds[t];
    if (totalDst) *totalDst = lds[t];
  }
}

// ---- build rank -> key map ----
__global__ void k_ukey(const unsigned* __restrict__ cnt, const unsigned* __restrict__ rank,
                       unsigned* __restrict__ ukeyArr) {
  int k = blockIdx.x * blockDim.x + threadIdx.x;
  if (k >= KSP) return;
  if (cnt[k]) ukeyArr[rank[k]] = (unsigned)k;
}

// ---- per-point: inv index + voxel-sorted permutation ----
__global__ void k_scatter(const unsigned* __restrict__ key, const unsigned* __restrict__ rank,
                          unsigned* __restrict__ inv, unsigned* __restrict__ ptCursor,
                          unsigned* __restrict__ ptOrder, int N) {
  int i = blockIdx.x * blockDim.x + threadIdx.x;
  if (i >= N) return;
  unsigned k = key[i];
  inv[i] = rank[k];
  unsigned posn = atomicAdd(&ptCursor[k], 1u);
  ptOrder[posn] = (unsigned)i;
}

// ---- compact per-rank segment starts (runs after k_scatter; cStart aliases ptCursor) ----
__global__ void k_cstart(const unsigned* __restrict__ cnt, const unsigned* __restrict__ rank,
                         const unsigned* __restrict__ ptStart, const unsigned* __restrict__ hdr,
                         unsigned* __restrict__ cStart, int N) {
  int k = blockIdx.x * blockDim.x + threadIdx.x;
  if (k >= KSP) return;
  if (cnt[k]) cStart[rank[k]] = ptStart[k];
  if (k == 0) cStart[hdr[3]] = (unsigned)N;
}

// ---- 8 lanes per voxel: feature max (2x float4 per lane = full 256B row) + pos mean.
//      8 independent voxels per wave -> 8 concurrent dependent-chains (latency hiding). ----
__global__ void __launch_bounds__(256) k_pool(const float4* __restrict__ x4,
                                              const float* __restrict__ pos,
                                              const unsigned* __restrict__ ptOrder,
                                              const unsigned* __restrict__ cStart,
                                              const unsigned* __restrict__ hdr,
                                              float* __restrict__ out) {
  unsigned gtid = blockIdx.x * blockDim.x + threadIdx.x;
  unsigned m = gtid >> 3;     // voxel id
  unsigned l = gtid & 7u;     // lane-in-group, covers features [l*4..l*4+3] and [(8+l)*4..]
  unsigned M = hdr[3];
  if (m >= M) return;
  unsigned start = cStart[m];
  unsigned n = cStart[m + 1] - start;
  const float NI = -__builtin_huge_valf();
  float4 a0 = make_float4(NI, NI, NI, NI);
  float4 a1 = a0;
  float psum = 0.0f;
  for (unsigned j = 0; j < n; ++j) {
    unsigned p = ptOrder[start + j];
    float4 v0 = x4[p * 16u + l];
    float4 v1 = x4[p * 16u + 8u + l];
    a0.x = fmaxf(a0.x, v0.x); a0.y = fmaxf(a0.y, v0.y);
    a0.z = fmaxf(a0.z, v0.z); a0.w = fmaxf(a0.w, v0.w);
    a1.x = fmaxf(a1.x, v1.x); a1.y = fmaxf(a1.y, v1.y);
    a1.z = fmaxf(a1.z, v1.z); a1.w = fmaxf(a1.w, v1.w);
    if (l < 3) psum += pos[3u * p + l];
  }
  float4* o4 = (float4*)out;
  o4[m * 16u + l] = a0;
  o4[m * 16u + 8u + l] = a1;
  if (l < 3) {
    unsigned long long O1 = 64ull * M;
    out[O1 + 3ull * m + l] = psum / (float)n;
  }
}

// ---- edges: partition histogram (LDS-aggregated) ----
__global__ void __launch_bounds__(256) k_ehist2(const int2* __restrict__ ei,
                                                const unsigned* __restrict__ inv,
                                                unsigned* __restrict__ partCnt, int E, int span) {
  __shared__ unsigned h[NPART];
  for (int i = threadIdx.x; i < NPART; i += 256) h[i] = 0;
  __syncthreads();
  int lo = blockIdx.x * span;
  int hi = min(E, lo + span);
  for (int e = lo + threadIdx.x; e < hi; e += 256) {
    int2 pr = ei[e];
    unsigned a = inv[pr.x], b = inv[pr.y];
    if (a != b) atomicAdd(&h[a >> 9], 1u);
  }
  __syncthreads();
  for (int i = threadIdx.x; i < NPART; i += 256) {
    unsigned v = h[i];
    if (v) atomicAdd(&partCnt[i], v);
  }
}

// ---- edges: partition scatter. Codes register-cached between the histogram and
//      write loops (single read of ei/inv); pStage entries are u32 code28. ----
__global__ void __launch_bounds__(256) k_pscatter(const int2* __restrict__ ei,
                                                  const unsigned* __restrict__ inv,
                                                  unsigned* __restrict__ partCursor,
                                                  unsigned* __restrict__ pStage,
                                                  int E) {
  __shared__ unsigned h[NPART];
  for (int i = threadIdx.x; i < NPART; i += 256) h[i] = 0;
  __syncthreads();
  int lo = blockIdx.x * (256 * PS_ITERS);
  unsigned long long codes[PS_ITERS];
#pragma unroll
  for (int it = 0; it < PS_ITERS; ++it) {
    codes[it] = ~0ull;
    int e = lo + threadIdx.x + it * 256;
    if (e < E) {
      int2 pr = ei[e];
      unsigned a = inv[pr.x], b = inv[pr.y];
      if (a != b) {
        codes[it] = ((unsigned long long)a << 19) | b;
        atomicAdd(&h[a >> 9], 1u);
      }
    }
  }
  __syncthreads();
  for (int i = threadIdx.x; i < NPART; i += 256) {
    unsigned v = h[i];
    h[i] = v ? atomicAdd(&partCursor[i], v) : 0u;
  }
  __syncthreads();
#pragma unroll
  for (int it = 0; it < PS_ITERS; ++it) {
    unsigned long long code = codes[it];
    if (code != ~0ull) {
      unsigned a = (unsigned)(code >> 19);
      unsigned off = atomicAdd(&h[a >> 9], 1u);
      pStage[off] = ((a & 511u) << 19) | ((unsigned)code & 0x7FFFFu);
    }
  }
}

// ---- per-partition: LDS counting-sort by srcLow, element-parallel rank-sort by dst,
//      global dedup flag + block-scan compaction. pStage entries: u32 code28. ----
__global__ void __launch_bounds__(256) k_bucket(unsigned* __restrict__ pStage,
                                                const unsigned* __restrict__ partStart,
                                                unsigned* __restrict__ partDistinct) {
  __shared__ unsigned dstL[SCAP2];
  __shared__ unsigned h[PB];
  __shared__ unsigned bbase[PB + 1];
  __shared__ unsigned stmp[256];
  unsigned p = blockIdx.x;
  unsigned s = partStart[p];
  unsigned c = partStart[p + 1] - s;
  unsigned t = threadIdx.x;
  for (int i = t; i < PB; i += 256) h[i] = 0;
  __syncthreads();
  if (c <= SCAP2) {
    const unsigned* src = pStage + s;
    // 1) histogram by srcLow
    for (unsigned i = t; i < c; i += 256) {
      atomicAdd(&h[src[i] >> 19], 1u);
    }
    __syncthreads();
    {  // 2) exclusive scan h -> bbase
      unsigned a = h[2 * t], b = h[2 * t + 1], sum = a + b;
      stmp[t] = sum;
      __syncthreads();
      for (int off = 1; off < 256; off <<= 1) {
        unsigned x = (t >= (unsigned)off) ? stmp[t - off] : 0u;
        __syncthreads(); stmp[t] += x; __syncthreads();
      }
      unsigned excl = stmp[t] - sum;
      bbase[2 * t] = excl; bbase[2 * t + 1] = excl + a;
      if (t == 255) bbase[PB] = stmp[255];
    }
    __syncthreads();
    for (int i = t; i < PB; i += 256) h[i] = bbase[i];  // h becomes cursor
    __syncthreads();
    // 3) scatter code28 into bucket-contiguous LDS
    for (unsigned i = t; i < c; i += 256) {
      unsigned code28 = src[i];
      unsigned off = atomicAdd(&h[code28 >> 19], 1u);
      dstL[off] = code28;
    }
    __syncthreads();
    // 4) element-parallel stable rank within bucket (independent, pipelined LDS reads)
    unsigned L = (c + 255) >> 8;  // elements per thread (blocked), <= 32
    unsigned vv[32], rr[32];
#pragma unroll
    for (unsigned k = 0; k < 32; ++k) {
      unsigned i = t * L + k;
      if (k < L && i < c) {
        unsigned v = dstL[i];
        unsigned b = v >> 19;
        unsigned blo = bbase[b], bhi = bbase[b + 1];
        unsigned r = blo;
        for (unsigned j = blo; j < bhi; ++j) {
          unsigned u = dstL[j];
          r += (u < v) || (u == v && j < i);
        }
        vv[k] = v; rr[k] = r;
      }
    }
    __syncthreads();
    // 5) in-place scatter to sorted position
#pragma unroll
    for (unsigned k = 0; k < 32; ++k) {
      unsigned i = t * L + k;
      if (k < L && i < c) dstL[rr[k]] = vv[k];
    }
    __syncthreads();
    // 6) dedup flags (whole partition is now sorted by code28) + block scan
    unsigned flm = 0, localSum = 0;
#pragma unroll
    for (unsigned k = 0; k < 32; ++k) {
      unsigned i = t * L + k;
      if (k < L && i < c) {
        unsigned v = dstL[i];
        unsigned pv = dstL[i - (i > 0 ? 1u : 0u)];
        unsigned f = (i == 0) | (pv != v);
        flm |= f << k;
        localSum += f;
      }
    }
    stmp[t] = localSum;
    __syncthreads();
    for (int off = 1; off < 256; off <<= 1) {
      unsigned x = (t >= (unsigned)off) ? stmp[t - off] : 0u;
      __syncthreads(); stmp[t] += x; __syncthreads();
    }
    unsigned pos = stmp[t] - localSum;
    // 7) compact distinct codes back to pStage (sorted by (src,dst))
#pragma unroll
    for (unsigned k = 0; k < 32; ++k) {
      unsigned i = t * L + k;
      if (k < L && i < c && ((flm >> k) & 1u)) {
        pStage[s + pos] = dstL[i];
        ++pos;
      }
    }
    if (t == 255) partDistinct[p] = stmp[255];
  } else if (t == 0) {  // fallback, statistically unreachable (mean+24sigma)
    unsigned* a = pStage + s;
    for (unsigned i = 1; i < c; ++i) {
      unsigned v = a[i];
      long long j = (long long)i - 1;
      while (j >= 0 && a[j] > v) { a[j + 1] = a[j]; --j; }
      a[j + 1] = v;
    }
    unsigned d = 0, prev = 0xFFFFFFFFu;
    for (unsigned i = 0; i < c; ++i) {
      unsigned v = a[i];
      if (i == 0 || v != prev) { a[d] = v; ++d; }
      prev = v;
    }
    partDistinct[p] = d;
  }
}

// ---- write deduped edges (reconstruct src from partition id) ----
__global__ void __launch_bounds__(256) k_ewriteP(const unsigned* __restrict__ pStage,
                                                 const unsigned* __restrict__ partStart,
                                                 const unsigned* __restrict__ partOut,
                                                 const unsigned* __restrict__ hdr,
                                                 float* __restrict__ out) {
  unsigned p = blockIdx.x;
  unsigned s = partStart[p];
  unsigned rbase = partOut[p];
  unsigned d = partOut[p + 1] - rbase;
  unsigned M = hdr[3];
  unsigned long long O2 = 67ull * M;
  unsigned pbase = p << 9;
  for (unsigned j = threadIdx.x; j < d; j += 256) {
    unsigned code = pStage[s + j];
    unsigned long long row = (unsigned long long)rbase + j;
    out[O2 + 2 * row + 0] = (float)(pbase | (code >> 19));
    out[O2 + 2 * row + 1] = (float)(code & 0x7FFFFu);
  }
}

// ---- self loops + new_batch ----
__global__ void k_final(const unsigned* __restrict__ ukeyArr, const unsigned* __restrict__ hdr,
                        float* __restrict__ out) {
  unsigned m = blockIdx.x * blockDim.x + threadIdx.x;
  unsigned M = hdr[3];
  if (m >= M) return;
  unsigned Ed = hdr[5];
  unsigned long long O2 = 67ull * M;
  unsigned long long row = (unsigned long long)Ed + m;
  float fm = (float)m;
  out[O2 + 2 * row + 0] = fm;
  out[O2 + 2 * row + 1] = fm;
  unsigned s0 = hdr[0] + 1, s1 = hdr[1] + 1, s2 = hdr[2] + 1;
  unsigned vol = s0 * s1 * s2;
  unsigned long long O3 = O2 + 2ull * (Ed + M);
  out[O3 + m] = (float)(ukeyArr[m] / vol);
}

extern "C" void kernel_launch(void* const* d_in, const int* in_sizes, int n_in,
                              void* d_out, int out_size, void* d_ws, size_t ws_size,
                              hipStream_t stream) {
  const float* x = (const float*)d_in[0];
  const float* pos = (const float*)d_in[1];
  const int* ei = (const int*)d_in[2];
  const int* batch = (const int*)d_in[3];
  float* out = (float*)d_out;
  int N = in_sizes[3];
  int E = in_sizes[2] / 2;

  unsigned* ws = (unsigned*)d_ws;
  // ws layout (u32 units)
  unsigned* hdr          = ws;                        // 64
  unsigned* cnt          = ws + 64;                   // KSP
  unsigned* partCnt      = cnt + KSP;                 // NPART
  unsigned* partDistinct = partCnt + NPART;           // NPART
  unsigned* rank         = partDistinct + NPART;      // KSP
  unsigned* ukeyArr      = rank + KSP;                // KSP
  unsigned* partStart    = ukeyArr + KSP;             // NPART+2
  unsigned* partCursor   = partStart + NPART + 2;     // NPART
  unsigned* partOut      = partCursor + NPART;        // NPART+2
  unsigned* chunkSums    = partOut + NPART + 2;       // 1024
  unsigned* key          = chunkSums + 1024;          // N
  unsigned* inv          = key + N;                   // N
  unsigned* pS32         = inv + ((N + 1) & ~1);      // 8B-aligned
  unsigned* pStage       = pS32;                      // E u32 (staged edge codes)
  // scratch aliased into the same region (dead before k_pscatter; stream-ordered):
  unsigned* ptStart  = pS32;                  // KSP
  unsigned* ptCursor = pS32 + KSP;            // KSP (becomes cStart after k_scatter)
  unsigned* ptOrder  = pS32 + 2 * KSP;        // N   (2*KSP+N u32 <= 2*E u32 region)
  unsigned* cStart   = ptCursor;              // M+1 <= KSP, built by k_cstart

  // zero: hdr + cnt + partCnt + partDistinct (contiguous).
  // d_out needs no zero-fill: every output byte is written (pooled_x+pos_mean by
  // k_pool, edges by k_ewriteP, loops+new_batch by k_final).
  hipMemsetAsync(ws, 0, (size_t)(64 + KSP + 2 * NPART) * 4, stream);

  const int B = 256;
  int gN = (N + B - 1) / B;
  int gK = (KSP + B - 1) / B;
  int gP = (int)(((long long)N * 8 + B - 1) / B);  // k_pool: 8 lanes per voxel, M<=N
  int ebH = 2048;                                  // k_ehist2 blocks
  int spanH = (E + ebH - 1) / ebH;
  int ebS = (E + 256 * PS_ITERS - 1) / (256 * PS_ITERS);  // k_pscatter blocks

  k_qmax<<<gN, B, 0, stream>>>(pos, hdr, N);
  k_keys<<<gN, B, 0, stream>>>(pos, batch, hdr, key, cnt, N);

  // rank = exclusive scan of presence(cnt); total -> hdr[3] = M
  scanA<<<NCHUNK, SCAN_BLOCK, 0, stream>>>(cnt, rank, chunkSums, KSP, 1);
  scanB<<<1, 1024, 0, stream>>>(chunkSums, &hdr[3], NCHUNK);
  scanC<<<gK, B, 0, stream>>>(rank, nullptr, chunkSums, KSP);

  // ptStart = exclusive scan of counts; cursor copy for the scatter
  scanA<<<NCHUNK, SCAN_BLOCK, 0, stream>>>(cnt, ptStart, chunkSums, KSP, 0);
  scanB<<<1, 1024, 0, stream>>>(chunkSums, &hdr[6], NCHUNK);
  scanC<<<gK, B, 0, stream>>>(ptStart, ptCursor, chunkSums, KSP);

  k_ukey<<<gK, B, 0, stream>>>(cnt, rank, ukeyArr);
  k_scatter<<<gN, B, 0, stream>>>(key, rank, inv, ptCursor, ptOrder, N);
  k_cstart<<<gK, B, 0, stream>>>(cnt, rank, ptStart, hdr, cStart, N);
  k_pool<<<gP, B, 0, stream>>>((const float4*)x, pos, ptOrder, cStart, hdr, out);

  // edges: partition -> LDS sort/dedup -> write
  const int2* ei2 = (const int2*)ei;
  k_ehist2<<<ebH, 256, 0, stream>>>(ei2, inv, partCnt, E, spanH);
  k_scan1024<<<1, NPART, 0, stream>>>(partCnt, partStart, partCursor, &hdr[4]);
  k_pscatter<<<ebS, 256, 0, stream>>>(ei2, inv, partCursor, pStage, E);
  k_bucket<<<NPART, 256, 0, stream>>>(pStage, partStart, partDistinct);
  k_scan1024<<<1, NPART, 0, stream>>>(partDistinct, partOut, nullptr, &hdr[5]);
  k_ewriteP<<<NPART, 256, 0, stream>>>(pStage, partStart, partOut, hdr, out);
  k_final<<<gK, B, 0, stream>>>(ukeyArr, hdr, out);

  (void)n_in; (void)ws_size;
}

// Round 5
// 493.030 us; speedup vs baseline: 1.2892x; 1.0564x over previous
//
#include <hip/hip_runtime.h>

// GraphPooling: voxel-grid pooling.
//  inputs: x[N,64] f32, pos[N,3] f32, edge_index[E,2] i32, batch[N] i32
//  outputs (concat, f32): pooled_x[M,64], pos_mean[M,3], ei_out[Ed+M,2], new_batch[M]
// Keyspace: key = ((b*s0+qx)*s1+qy)*s2+qz < 16*32*32*32 = 524288.
// Pooling: voxel-sorted point permutation (ptOrder) + compact segment starts
// (cStart[m]) + 8-lanes-per-voxel segment reduce.
// Edge pipeline: partition by src>>8 (2048 partitions, ~2.9k edges each).
// pStage holds u32 code27 = (srcLow8<<19)|dst — partition id supplies high bits.
// k_bucket: LDS counting-sort by srcLow + element-parallel rank-sort by dst,
// dedup flag + block-scan compaction. LDS ~19.5KB -> 8 blocks/CU.

#define KSP 524288
#define SCAN_BLOCK 256
#define SCAN_ITEMS 16
#define SCAN_CHUNK 4096            // SCAN_BLOCK * SCAN_ITEMS
#define NCHUNK (KSP / SCAN_CHUNK)  // 128
#define NPART 2048
#define PSHIFT 8                   // partition = src >> PSHIFT
#define PB 256                     // voxel ranks per partition (KSP/NPART)
#define SCAP2 4096                 // LDS cap: edges per partition (mean ~2.9k, sigma ~54)
#define PS_ITERS 16                // edges per thread in k_pscatter

// ws header slots (u32): [0..2]=max qpos, [3]=M, [4]=validE, [5]=Ed

// ---- per-point: max of quantized coords ----
__global__ void k_qmax(const float* __restrict__ pos, unsigned* hdr, int N) {
  __shared__ unsigned sm[3];
  if (threadIdx.x < 3) sm[threadIdx.x] = 0;
  __syncthreads();
  int i = blockIdx.x * blockDim.x + threadIdx.x;
  if (i < N) {
    int q0 = (int)floorf(pos[3 * i + 0] * 0.25f);
    int q1 = (int)floorf(pos[3 * i + 1] * 0.25f);
    int q2 = (int)floorf(pos[3 * i + 2] * 0.25f);
    atomicMax(&sm[0], (unsigned)q0);
    atomicMax(&sm[1], (unsigned)q1);
    atomicMax(&sm[2], (unsigned)q2);
  }
  __syncthreads();
  if (threadIdx.x < 3) atomicMax(&hdr[threadIdx.x], sm[threadIdx.x]);
}

// ---- per-point: voxel key + histogram ----
__global__ void k_keys(const float* __restrict__ pos, const int* __restrict__ batch,
                       const unsigned* __restrict__ hdr, unsigned* __restrict__ key,
                       unsigned* __restrict__ cnt, int N) {
  int i = blockIdx.x * blockDim.x + threadIdx.x;
  if (i >= N) return;
  unsigned s0 = hdr[0] + 1, s1 = hdr[1] + 1, s2 = hdr[2] + 1;
  unsigned q0 = (unsigned)(int)floorf(pos[3 * i + 0] * 0.25f);
  unsigned q1 = (unsigned)(int)floorf(pos[3 * i + 1] * 0.25f);
  unsigned q2 = (unsigned)(int)floorf(pos[3 * i + 2] * 0.25f);
  unsigned k = (((unsigned)batch[i] * s0 + q0) * s1 + q1) * s2 + q2;
  key[i] = k;
  atomicAdd(&cnt[k], 1u);
}

// ---- fused dual exclusive scan over KSP: presence(cnt) -> rank, cnt -> ptStart ----
__global__ void scanA2(const unsigned* __restrict__ in, unsigned* __restrict__ outRank,
                       unsigned* __restrict__ outStart, unsigned* __restrict__ chunkP,
                       unsigned* __restrict__ chunkC, int n) {
  __shared__ unsigned ldsP[SCAN_BLOCK];
  __shared__ unsigned ldsC[SCAN_BLOCK];
  int tbase = blockIdx.x * SCAN_CHUNK + threadIdx.x * SCAN_ITEMS;
  unsigned valsP[SCAN_ITEMS], valsC[SCAN_ITEMS];
  unsigned sp = 0, sc = 0;
  for (int i = 0; i < SCAN_ITEMS; ++i) {
    unsigned v = 0;
    int idx = tbase + i;
    if (idx < n) v = in[idx];
    valsP[i] = sp; valsC[i] = sc;
    sp += v ? 1u : 0u;
    sc += v;
  }
  ldsP[threadIdx.x] = sp; ldsC[threadIdx.x] = sc;
  __syncthreads();
  for (int off = 1; off < SCAN_BLOCK; off <<= 1) {
    unsigned tp = (threadIdx.x >= (unsigned)off) ? ldsP[threadIdx.x - off] : 0u;
    unsigned tc = (threadIdx.x >= (unsigned)off) ? ldsC[threadIdx.x - off] : 0u;
    __syncthreads();
    ldsP[threadIdx.x] += tp; ldsC[threadIdx.x] += tc;
    __syncthreads();
  }
  unsigned exP = ldsP[threadIdx.x] - sp;
  unsigned exC = ldsC[threadIdx.x] - sc;
  for (int i = 0; i < SCAN_ITEMS; ++i) {
    int idx = tbase + i;
    if (idx < n) { outRank[idx] = exP + valsP[i]; outStart[idx] = exC + valsC[i]; }
  }
  if (threadIdx.x == SCAN_BLOCK - 1) {
    chunkP[blockIdx.x] = ldsP[SCAN_BLOCK - 1];
    chunkC[blockIdx.x] = ldsC[SCAN_BLOCK - 1];
  }
}

__global__ void scanB2(unsigned* chunkP, unsigned* chunkC, unsigned* mDst) {
  __shared__ unsigned lp[NCHUNK];
  __shared__ unsigned lc[NCHUNK];
  unsigned t = threadIdx.x;  // NCHUNK threads
  unsigned vp = chunkP[t], vc = chunkC[t];
  lp[t] = vp; lc[t] = vc;
  __syncthreads();
  for (int off = 1; off < NCHUNK; off <<= 1) {
    unsigned xp = (t >= (unsigned)off) ? lp[t - off] : 0u;
    unsigned xc = (t >= (unsigned)off) ? lc[t - off] : 0u;
    __syncthreads();
    lp[t] += xp; lc[t] += xc;
    __syncthreads();
  }
  chunkP[t] = lp[t] - vp;
  chunkC[t] = lc[t] - vc;
  if (t == NCHUNK - 1 && mDst) *mDst = lp[NCHUNK - 1];
}

__global__ void scanC2(unsigned* __restrict__ rank, unsigned* __restrict__ ptStart,
                       const unsigned* __restrict__ chunkP, const unsigned* __restrict__ chunkC,
                       int n) {
  int idx = blockIdx.x * blockDim.x + threadIdx.x;
  if (idx >= n) return;
  int ch = idx / SCAN_CHUNK;
  rank[idx] += chunkP[ch];
  ptStart[idx] += chunkC[ch];
}

// ---- single-block exclusive scan of NPART entries (1024 thr x 2 items) ----
__global__ void k_scanP(const unsigned* __restrict__ in, unsigned* __restrict__ outStart,
                        unsigned* __restrict__ outCursor, unsigned* __restrict__ totalDst) {
  __shared__ unsigned lds[1024];
  unsigned t = threadIdx.x;
  unsigned a = in[2 * t], b = in[2 * t + 1];
  unsigned sum = a + b;
  lds[t] = sum;
  __syncthreads();
  for (int off = 1; off < 1024; off <<= 1) {
    unsigned x = (t >= (unsigned)off) ? lds[t - off] : 0u;
    __syncthreads();
    lds[t] += x;
    __syncthreads();
  }
  unsigned excl = lds[t] - sum;
  outStart[2 * t] = excl;
  outStart[2 * t + 1] = excl + a;
  if (outCursor) { outCursor[2 * t] = excl; outCursor[2 * t + 1] = excl + a; }
  if (t == 1023) {
    outStart[NPART] = lds[1023];
    if (totalDst) *totalDst = lds[1023];
  }
}

// ---- rank -> key map + compact segment starts (before k_scatter mutates ptStart) ----
__global__ void k_ukey(const unsigned* __restrict__ cnt, const unsigned* __restrict__ rank,
                       const unsigned* __restrict__ ptStart, const unsigned* __restrict__ hdr,
                       unsigned* __restrict__ ukeyArr, unsigned* __restrict__ cStart, int N) {
  int k = blockIdx.x * blockDim.x + threadIdx.x;
  if (k >= KSP) return;
  if (cnt[k]) {
    unsigned r = rank[k];
    ukeyArr[r] = (unsigned)k;
    cStart[r] = ptStart[k];
  }
  if (k == 0) cStart[hdr[3]] = (unsigned)N;
}

// ---- per-point: inv index + voxel-sorted permutation (ptStart doubles as cursor) ----
__global__ void k_scatter(const unsigned* __restrict__ key, const unsigned* __restrict__ rank,
                          unsigned* __restrict__ inv, unsigned* __restrict__ ptStart,
                          unsigned* __restrict__ ptOrder, int N) {
  int i = blockIdx.x * blockDim.x + threadIdx.x;
  if (i >= N) return;
  unsigned k = key[i];
  inv[i] = rank[k];
  unsigned posn = atomicAdd(&ptStart[k], 1u);
  ptOrder[posn] = (unsigned)i;
}

// ---- 8 lanes per voxel: feature max (2x float4 per lane = full 256B row) + pos mean ----
__global__ void __launch_bounds__(256) k_pool(const float4* __restrict__ x4,
                                              const float* __restrict__ pos,
                                              const unsigned* __restrict__ ptOrder,
                                              const unsigned* __restrict__ cStart,
                                              const unsigned* __restrict__ hdr,
                                              float* __restrict__ out) {
  unsigned gtid = blockIdx.x * blockDim.x + threadIdx.x;
  unsigned m = gtid >> 3;     // voxel id
  unsigned l = gtid & 7u;     // lane-in-group
  unsigned M = hdr[3];
  if (m >= M) return;
  unsigned start = cStart[m];
  unsigned n = cStart[m + 1] - start;
  const float NI = -__builtin_huge_valf();
  float4 a0 = make_float4(NI, NI, NI, NI);
  float4 a1 = a0;
  float psum = 0.0f;
  for (unsigned j = 0; j < n; ++j) {
    unsigned p = ptOrder[start + j];
    float4 v0 = x4[p * 16u + l];
    float4 v1 = x4[p * 16u + 8u + l];
    a0.x = fmaxf(a0.x, v0.x); a0.y = fmaxf(a0.y, v0.y);
    a0.z = fmaxf(a0.z, v0.z); a0.w = fmaxf(a0.w, v0.w);
    a1.x = fmaxf(a1.x, v1.x); a1.y = fmaxf(a1.y, v1.y);
    a1.z = fmaxf(a1.z, v1.z); a1.w = fmaxf(a1.w, v1.w);
    if (l < 3) psum += pos[3u * p + l];
  }
  float4* o4 = (float4*)out;
  o4[m * 16u + l] = a0;
  o4[m * 16u + 8u + l] = a1;
  if (l < 3) {
    unsigned long long O1 = 64ull * M;
    out[O1 + 3ull * m + l] = psum / (float)n;
  }
}

// ---- edges: partition histogram (LDS-aggregated) ----
__global__ void __launch_bounds__(256) k_ehist2(const int2* __restrict__ ei,
                                                const unsigned* __restrict__ inv,
                                                unsigned* __restrict__ partCnt, int E, int span) {
  __shared__ unsigned h[NPART];
  for (int i = threadIdx.x; i < NPART; i += 256) h[i] = 0;
  __syncthreads();
  int lo = blockIdx.x * span;
  int hi = min(E, lo + span);
  for (int e = lo + threadIdx.x; e < hi; e += 256) {
    int2 pr = ei[e];
    unsigned a = inv[pr.x], b = inv[pr.y];
    if (a != b) atomicAdd(&h[a >> PSHIFT], 1u);
  }
  __syncthreads();
  for (int i = threadIdx.x; i < NPART; i += 256) {
    unsigned v = h[i];
    if (v) atomicAdd(&partCnt[i], v);
  }
}

// ---- edges: partition scatter; codes register-cached; pStage entries u32 code27 ----
__global__ void __launch_bounds__(256) k_pscatter(const int2* __restrict__ ei,
                                                  const unsigned* __restrict__ inv,
                                                  unsigned* __restrict__ partCursor,
                                                  unsigned* __restrict__ pStage,
                                                  int E) {
  __shared__ unsigned h[NPART];
  for (int i = threadIdx.x; i < NPART; i += 256) h[i] = 0;
  __syncthreads();
  int lo = blockIdx.x * (256 * PS_ITERS);
  unsigned long long codes[PS_ITERS];
#pragma unroll
  for (int it = 0; it < PS_ITERS; ++it) {
    codes[it] = ~0ull;
    int e = lo + threadIdx.x + it * 256;
    if (e < E) {
      int2 pr = ei[e];
      unsigned a = inv[pr.x], b = inv[pr.y];
      if (a != b) {
        codes[it] = ((unsigned long long)a << 19) | b;
        atomicAdd(&h[a >> PSHIFT], 1u);
      }
    }
  }
  __syncthreads();
  for (int i = threadIdx.x; i < NPART; i += 256) {
    unsigned v = h[i];
    h[i] = v ? atomicAdd(&partCursor[i], v) : 0u;
  }
  __syncthreads();
#pragma unroll
  for (int it = 0; it < PS_ITERS; ++it) {
    unsigned long long code = codes[it];
    if (code != ~0ull) {
      unsigned a = (unsigned)(code >> 19);
      unsigned off = atomicAdd(&h[a >> PSHIFT], 1u);
      pStage[off] = ((a & (PB - 1u)) << 19) | ((unsigned)code & 0x7FFFFu);
    }
  }
}

// ---- per-partition: LDS counting-sort by srcLow, element-parallel rank-sort by dst,
//      dedup flag + block-scan compaction. LDS ~19.5KB -> 8 blocks/CU. ----
__global__ void __launch_bounds__(256) k_bucket(unsigned* __restrict__ pStage,
                                                const unsigned* __restrict__ partStart,
                                                unsigned* __restrict__ partDistinct) {
  __shared__ unsigned dstL[SCAP2];
  __shared__ unsigned h[PB];
  __shared__ unsigned bbase[PB + 1];
  __shared__ unsigned stmp[256];
  unsigned p = blockIdx.x;
  unsigned s = partStart[p];
  unsigned c = partStart[p + 1] - s;
  unsigned t = threadIdx.x;
  h[t] = 0;  // PB == 256 == blockDim
  __syncthreads();
  if (c <= SCAP2) {
    const unsigned* src = pStage + s;
    // 1) histogram by srcLow
    for (unsigned i = t; i < c; i += 256) atomicAdd(&h[src[i] >> 19], 1u);
    __syncthreads();
    {  // 2) exclusive scan h -> bbase (256 entries, one per thread)
      unsigned v = h[t];
      stmp[t] = v;
      __syncthreads();
      for (int off = 1; off < 256; off <<= 1) {
        unsigned x = (t >= (unsigned)off) ? stmp[t - off] : 0u;
        __syncthreads(); stmp[t] += x; __syncthreads();
      }
      bbase[t] = stmp[t] - v;
      if (t == 255) bbase[PB] = stmp[255];
    }
    __syncthreads();
    h[t] = bbase[t];  // h becomes cursor
    __syncthreads();
    // 3) scatter code into bucket-contiguous LDS
    for (unsigned i = t; i < c; i += 256) {
      unsigned code = src[i];
      unsigned off = atomicAdd(&h[code >> 19], 1u);
      dstL[off] = code;
    }
    __syncthreads();
    // 4) element-parallel stable rank within bucket
    unsigned L = (c + 255) >> 8;  // elements per thread (blocked), <= 16
    unsigned vv[16], rr[16];
#pragma unroll
    for (unsigned k = 0; k < 16; ++k) {
      unsigned i = t * L + k;
      if (k < L && i < c) {
        unsigned v = dstL[i];
        unsigned b = v >> 19;
        unsigned blo = bbase[b], bhi = bbase[b + 1];
        unsigned r = blo;
        for (unsigned j = blo; j < bhi; ++j) {
          unsigned u = dstL[j];
          r += (u < v) || (u == v && j < i);
        }
        vv[k] = v; rr[k] = r;
      }
    }
    __syncthreads();
    // 5) in-place scatter to sorted position
#pragma unroll
    for (unsigned k = 0; k < 16; ++k) {
      unsigned i = t * L + k;
      if (k < L && i < c) dstL[rr[k]] = vv[k];
    }
    __syncthreads();
    // 6) dedup flags (partition now sorted by code) + block scan
    unsigned flm = 0, localSum = 0;
#pragma unroll
    for (unsigned k = 0; k < 16; ++k) {
      unsigned i = t * L + k;
      if (k < L && i < c) {
        unsigned v = dstL[i];
        unsigned pv = dstL[i - (i > 0 ? 1u : 0u)];
        unsigned f = (i == 0) | (pv != v);
        flm |= f << k;
        localSum += f;
      }
    }
    stmp[t] = localSum;
    __syncthreads();
    for (int off = 1; off < 256; off <<= 1) {
      unsigned x = (t >= (unsigned)off) ? stmp[t - off] : 0u;
      __syncthreads(); stmp[t] += x; __syncthreads();
    }
    unsigned pos = stmp[t] - localSum;
    // 7) compact distinct codes back to pStage (sorted by (src,dst))
#pragma unroll
    for (unsigned k = 0; k < 16; ++k) {
      unsigned i = t * L + k;
      if (k < L && i < c && ((flm >> k) & 1u)) {
        pStage[s + pos] = dstL[i];
        ++pos;
      }
    }
    if (t == 255) partDistinct[p] = stmp[255];
  } else if (t == 0) {  // fallback, statistically unreachable (mean+20sigma)
    unsigned* a = pStage + s;
    for (unsigned i = 1; i < c; ++i) {
      unsigned v = a[i];
      long long j = (long long)i - 1;
      while (j >= 0 && a[j] > v) { a[j + 1] = a[j]; --j; }
      a[j + 1] = v;
    }
    unsigned d = 0, prev = 0xFFFFFFFFu;
    for (unsigned i = 0; i < c; ++i) {
      unsigned v = a[i];
      if (i == 0 || v != prev) { a[d] = v; ++d; }
      prev = v;
    }
    partDistinct[p] = d;
  }
}

// ---- write deduped edges (reconstruct src from partition id) ----
__global__ void __launch_bounds__(256) k_ewriteP(const unsigned* __restrict__ pStage,
                                                 const unsigned* __restrict__ partStart,
                                                 const unsigned* __restrict__ partOut,
                                                 const unsigned* __restrict__ hdr,
                                                 float* __restrict__ out) {
  unsigned p = blockIdx.x;
  unsigned s = partStart[p];
  unsigned rbase = partOut[p];
  unsigned d = partOut[p + 1] - rbase;
  unsigned M = hdr[3];
  unsigned long long O2 = 67ull * M;
  unsigned pbase = p << PSHIFT;
  for (unsigned j = threadIdx.x; j < d; j += 256) {
    unsigned code = pStage[s + j];
    unsigned long long row = (unsigned long long)rbase + j;
    out[O2 + 2 * row + 0] = (float)(pbase | (code >> 19));
    out[O2 + 2 * row + 1] = (float)(code & 0x7FFFFu);
  }
}

// ---- self loops + new_batch ----
__global__ void k_final(const unsigned* __restrict__ ukeyArr, const unsigned* __restrict__ hdr,
                        float* __restrict__ out) {
  unsigned m = blockIdx.x * blockDim.x + threadIdx.x;
  unsigned M = hdr[3];
  if (m >= M) return;
  unsigned Ed = hdr[5];
  unsigned long long O2 = 67ull * M;
  unsigned long long row = (unsigned long long)Ed + m;
  float fm = (float)m;
  out[O2 + 2 * row + 0] = fm;
  out[O2 + 2 * row + 1] = fm;
  unsigned s0 = hdr[0] + 1, s1 = hdr[1] + 1, s2 = hdr[2] + 1;
  unsigned vol = s0 * s1 * s2;
  unsigned long long O3 = O2 + 2ull * (Ed + M);
  out[O3 + m] = (float)(ukeyArr[m] / vol);
}

extern "C" void kernel_launch(void* const* d_in, const int* in_sizes, int n_in,
                              void* d_out, int out_size, void* d_ws, size_t ws_size,
                              hipStream_t stream) {
  const float* x = (const float*)d_in[0];
  const float* pos = (const float*)d_in[1];
  const int* ei = (const int*)d_in[2];
  const int* batch = (const int*)d_in[3];
  float* out = (float*)d_out;
  int N = in_sizes[3];
  int E = in_sizes[2] / 2;

  unsigned* ws = (unsigned*)d_ws;
  // ws layout (u32 units)
  unsigned* hdr          = ws;                        // 64
  unsigned* cnt          = ws + 64;                   // KSP
  unsigned* partCnt      = cnt + KSP;                 // NPART
  unsigned* partDistinct = partCnt + NPART;           // NPART
  unsigned* rank         = partDistinct + NPART;      // KSP
  unsigned* ukeyArr      = rank + KSP;                // KSP
  unsigned* cStart       = ukeyArr + KSP;             // KSP+2 (M+1 used)
  unsigned* partStart    = cStart + KSP + 2;          // NPART+2
  unsigned* partCursor   = partStart + NPART + 2;     // NPART
  unsigned* partOut      = partCursor + NPART;        // NPART+2
  unsigned* chunkP       = partOut + NPART + 2;       // 1024 (NCHUNK used)
  unsigned* chunkC       = chunkP + 1024;             // 1024
  unsigned* key          = chunkC + 1024;             // N
  unsigned* inv          = key + N;                   // N
  unsigned* pS32         = inv + ((N + 1) & ~1);      // 8B-aligned
  unsigned* pStage       = pS32;                      // E u32 (staged edge codes)
  // scratch aliased into the same region (dead before k_pscatter; stream-ordered):
  unsigned* ptStart  = pS32;                 // KSP (scan output; mutated to cursors by k_scatter)
  unsigned* ptOrder  = pS32 + KSP;           // N   (KSP+N u32 <= E u32 region)

  // zero: hdr + cnt + partCnt + partDistinct (contiguous).
  hipMemsetAsync(ws, 0, (size_t)(64 + KSP + 2 * NPART) * 4, stream);

  const int B = 256;
  int gN = (N + B - 1) / B;
  int gK = (KSP + B - 1) / B;
  int gP = (int)(((long long)N * 8 + B - 1) / B);  // k_pool: 8 lanes per voxel, M<=N
  int ebH = 2048;                                  // k_ehist2 blocks
  int spanH = (E + ebH - 1) / ebH;
  int ebS = (E + 256 * PS_ITERS - 1) / (256 * PS_ITERS);  // k_pscatter blocks

  k_qmax<<<gN, B, 0, stream>>>(pos, hdr, N);
  k_keys<<<gN, B, 0, stream>>>(pos, batch, hdr, key, cnt, N);

  // fused dual scan: rank (presence) + ptStart (counts); hdr[3] = M
  scanA2<<<NCHUNK, SCAN_BLOCK, 0, stream>>>(cnt, rank, ptStart, chunkP, chunkC, KSP);
  scanB2<<<1, NCHUNK, 0, stream>>>(chunkP, chunkC, &hdr[3]);
  scanC2<<<gK, B, 0, stream>>>(rank, ptStart, chunkP, chunkC, KSP);

  k_ukey<<<gK, B, 0, stream>>>(cnt, rank, ptStart, hdr, ukeyArr, cStart, N);
  k_scatter<<<gN, B, 0, stream>>>(key, rank, inv, ptStart, ptOrder, N);
  k_pool<<<gP, B, 0, stream>>>((const float4*)x, pos, ptOrder, cStart, hdr, out);

  // edges: partition -> LDS sort/dedup -> write
  const int2* ei2 = (const int2*)ei;
  k_ehist2<<<ebH, 256, 0, stream>>>(ei2, inv, partCnt, E, spanH);
  k_scanP<<<1, 1024, 0, stream>>>(partCnt, partStart, partCursor, &hdr[4]);
  k_pscatter<<<ebS, 256, 0, stream>>>(ei2, inv, partCursor, pStage, E);
  k_bucket<<<NPART, 256, 0, stream>>>(pStage, partStart, partDistinct);
  k_scanP<<<1, 1024, 0, stream>>>(partDistinct, partOut, nullptr, &hdr[5]);
  k_ewriteP<<<NPART, 256, 0, stream>>>(pStage, partStart, partOut, hdr, out);
  k_final<<<gK, B, 0, stream>>>(ukeyArr, hdr, out);

  (void)n_in; (void)ws_size;
}

// Round 6
// 458.931 us; speedup vs baseline: 1.3850x; 1.0743x over previous
//
#include <hip/hip_runtime.h>

// GraphPooling: voxel-grid pooling.
//  inputs: x[N,64] f32, pos[N,3] f32, edge_index[E,2] i32, batch[N] i32
//  outputs (concat, f32): pooled_x[M,64], pos_mean[M,3], ei_out[Ed+M,2], new_batch[M]
// Keyspace: key = ((b*32+qx)*32+qy)*32+qz < 524288 (strides hardcoded: pos<128 so
// qpos<32; any stride >= max+1 preserves the lex order that defines rank order,
// and new_batch = key/32768 is exact).
// Pooling: voxel-sorted point permutation (ptOrder) + compact segment starts
// (cStart[m]) + 8-lanes-per-voxel segment reduce.
// Edge pipeline (two-level scatter, all store runs >= 0.5KB):
//   pscat1: ei -> 64 coarse buckets (src>>13), code32=(srcLow13<<19)|dst
//   pscat2: coarse stream -> 2048 fine partitions (src>>8), code27
//   k_bucket: LDS counting-sort by srcLow8 + element-parallel rank-sort by dst,
//   dedup flag + block-scan compaction.

#define KSP 524288
#define SCAN_BLOCK 256
#define SCAN_ITEMS 16
#define SCAN_CHUNK 4096            // SCAN_BLOCK * SCAN_ITEMS
#define NCHUNK (KSP / SCAN_CHUNK)  // 128
#define NPART 2048
#define PSHIFT 8                   // partition = src >> PSHIFT
#define PB 256                     // voxel ranks per partition (KSP/NPART)
#define SCAP2 4096                 // LDS cap: edges per partition (mean ~2.9k)
#define NCOARSE 64
#define CSHIFT 13                  // coarse bucket = src >> CSHIFT
#define CMASK 8191u
#define PS_ITERS 16                // edges per thread in pscat1/pscat2

// ws header slots (u32): [3]=M, [4]=validE, [5]=Ed

// ---- per-point: voxel key + histogram (strides hardcoded to 32) ----
__global__ void k_keys(const float* __restrict__ pos, const int* __restrict__ batch,
                       unsigned* __restrict__ key, unsigned* __restrict__ cnt, int N) {
  int i = blockIdx.x * blockDim.x + threadIdx.x;
  if (i >= N) return;
  unsigned q0 = (unsigned)(int)floorf(pos[3 * i + 0] * 0.25f);
  unsigned q1 = (unsigned)(int)floorf(pos[3 * i + 1] * 0.25f);
  unsigned q2 = (unsigned)(int)floorf(pos[3 * i + 2] * 0.25f);
  unsigned k = ((((((unsigned)batch[i] << 5) | q0) << 5) | q1) << 5) | q2;
  key[i] = k;
  atomicAdd(&cnt[k], 1u);
}

// ---- fused dual exclusive scan over KSP: presence(cnt) -> rank, cnt -> ptStart ----
__global__ void scanA2(const unsigned* __restrict__ in, unsigned* __restrict__ outRank,
                       unsigned* __restrict__ outStart, unsigned* __restrict__ chunkP,
                       unsigned* __restrict__ chunkC, int n) {
  __shared__ unsigned ldsP[SCAN_BLOCK];
  __shared__ unsigned ldsC[SCAN_BLOCK];
  int tbase = blockIdx.x * SCAN_CHUNK + threadIdx.x * SCAN_ITEMS;
  unsigned valsP[SCAN_ITEMS], valsC[SCAN_ITEMS];
  unsigned sp = 0, sc = 0;
  for (int i = 0; i < SCAN_ITEMS; ++i) {
    unsigned v = 0;
    int idx = tbase + i;
    if (idx < n) v = in[idx];
    valsP[i] = sp; valsC[i] = sc;
    sp += v ? 1u : 0u;
    sc += v;
  }
  ldsP[threadIdx.x] = sp; ldsC[threadIdx.x] = sc;
  __syncthreads();
  for (int off = 1; off < SCAN_BLOCK; off <<= 1) {
    unsigned tp = (threadIdx.x >= (unsigned)off) ? ldsP[threadIdx.x - off] : 0u;
    unsigned tc = (threadIdx.x >= (unsigned)off) ? ldsC[threadIdx.x - off] : 0u;
    __syncthreads();
    ldsP[threadIdx.x] += tp; ldsC[threadIdx.x] += tc;
    __syncthreads();
  }
  unsigned exP = ldsP[threadIdx.x] - sp;
  unsigned exC = ldsC[threadIdx.x] - sc;
  for (int i = 0; i < SCAN_ITEMS; ++i) {
    int idx = tbase + i;
    if (idx < n) { outRank[idx] = exP + valsP[i]; outStart[idx] = exC + valsC[i]; }
  }
  if (threadIdx.x == SCAN_BLOCK - 1) {
    chunkP[blockIdx.x] = ldsP[SCAN_BLOCK - 1];
    chunkC[blockIdx.x] = ldsC[SCAN_BLOCK - 1];
  }
}

__global__ void scanB2(unsigned* chunkP, unsigned* chunkC, unsigned* mDst) {
  __shared__ unsigned lp[NCHUNK];
  __shared__ unsigned lc[NCHUNK];
  unsigned t = threadIdx.x;  // NCHUNK threads
  unsigned vp = chunkP[t], vc = chunkC[t];
  lp[t] = vp; lc[t] = vc;
  __syncthreads();
  for (int off = 1; off < NCHUNK; off <<= 1) {
    unsigned xp = (t >= (unsigned)off) ? lp[t - off] : 0u;
    unsigned xc = (t >= (unsigned)off) ? lc[t - off] : 0u;
    __syncthreads();
    lp[t] += xp; lc[t] += xc;
    __syncthreads();
  }
  chunkP[t] = lp[t] - vp;
  chunkC[t] = lc[t] - vc;
  if (t == NCHUNK - 1 && mDst) *mDst = lp[NCHUNK - 1];
}

__global__ void scanC2(unsigned* __restrict__ rank, unsigned* __restrict__ ptStart,
                       const unsigned* __restrict__ chunkP, const unsigned* __restrict__ chunkC,
                       int n) {
  int idx = blockIdx.x * blockDim.x + threadIdx.x;
  if (idx >= n) return;
  int ch = idx / SCAN_CHUNK;
  rank[idx] += chunkP[ch];
  ptStart[idx] += chunkC[ch];
}

// ---- single-block exclusive scan of NPART entries (1024 thr x 2 items).
//      Also seeds the 64 coarse-bucket cursors (ccur[c] = excl at index 32c). ----
__global__ void k_scanP(const unsigned* __restrict__ in, unsigned* __restrict__ outStart,
                        unsigned* __restrict__ outCursor, unsigned* __restrict__ ccur,
                        unsigned* __restrict__ totalDst) {
  __shared__ unsigned lds[1024];
  unsigned t = threadIdx.x;
  unsigned a = in[2 * t], b = in[2 * t + 1];
  unsigned sum = a + b;
  lds[t] = sum;
  __syncthreads();
  for (int off = 1; off < 1024; off <<= 1) {
    unsigned x = (t >= (unsigned)off) ? lds[t - off] : 0u;
    __syncthreads();
    lds[t] += x;
    __syncthreads();
  }
  unsigned excl = lds[t] - sum;
  outStart[2 * t] = excl;
  outStart[2 * t + 1] = excl + a;
  if (outCursor) { outCursor[2 * t] = excl; outCursor[2 * t + 1] = excl + a; }
  if (ccur && (t & 15u) == 0) ccur[t >> 4] = excl;  // index 2t ≡ 0 mod 32
  if (t == 1023) {
    outStart[NPART] = lds[1023];
    if (totalDst) *totalDst = lds[1023];
  }
}

// ---- rank -> key map + compact segment starts (before k_scatter mutates ptStart) ----
__global__ void k_ukey(const unsigned* __restrict__ cnt, const unsigned* __restrict__ rank,
                       const unsigned* __restrict__ ptStart, const unsigned* __restrict__ hdr,
                       unsigned* __restrict__ ukeyArr, unsigned* __restrict__ cStart, int N) {
  int k = blockIdx.x * blockDim.x + threadIdx.x;
  if (k >= KSP) return;
  if (cnt[k]) {
    unsigned r = rank[k];
    ukeyArr[r] = (unsigned)k;
    cStart[r] = ptStart[k];
  }
  if (k == 0) cStart[hdr[3]] = (unsigned)N;
}

// ---- per-point: inv index + voxel-sorted permutation (ptStart doubles as cursor) ----
__global__ void k_scatter(const unsigned* __restrict__ key, const unsigned* __restrict__ rank,
                          unsigned* __restrict__ inv, unsigned* __restrict__ ptStart,
                          unsigned* __restrict__ ptOrder, int N) {
  int i = blockIdx.x * blockDim.x + threadIdx.x;
  if (i >= N) return;
  unsigned k = key[i];
  inv[i] = rank[k];
  unsigned posn = atomicAdd(&ptStart[k], 1u);
  ptOrder[posn] = (unsigned)i;
}

// ---- 8 lanes per voxel: feature max (2x float4 per lane = full 256B row) + pos mean ----
__global__ void __launch_bounds__(256) k_pool(const float4* __restrict__ x4,
                                              const float* __restrict__ pos,
                                              const unsigned* __restrict__ ptOrder,
                                              const unsigned* __restrict__ cStart,
                                              const unsigned* __restrict__ hdr,
                                              float* __restrict__ out) {
  unsigned gtid = blockIdx.x * blockDim.x + threadIdx.x;
  unsigned m = gtid >> 3;     // voxel id
  unsigned l = gtid & 7u;     // lane-in-group
  unsigned M = hdr[3];
  if (m >= M) return;
  unsigned start = cStart[m];
  unsigned n = cStart[m + 1] - start;
  const float NI = -__builtin_huge_valf();
  float4 a0 = make_float4(NI, NI, NI, NI);
  float4 a1 = a0;
  float psum = 0.0f;
  for (unsigned j = 0; j < n; ++j) {
    unsigned p = ptOrder[start + j];
    float4 v0 = x4[p * 16u + l];
    float4 v1 = x4[p * 16u + 8u + l];
    a0.x = fmaxf(a0.x, v0.x); a0.y = fmaxf(a0.y, v0.y);
    a0.z = fmaxf(a0.z, v0.z); a0.w = fmaxf(a0.w, v0.w);
    a1.x = fmaxf(a1.x, v1.x); a1.y = fmaxf(a1.y, v1.y);
    a1.z = fmaxf(a1.z, v1.z); a1.w = fmaxf(a1.w, v1.w);
    if (l < 3) psum += pos[3u * p + l];
  }
  float4* o4 = (float4*)out;
  o4[m * 16u + l] = a0;
  o4[m * 16u + 8u + l] = a1;
  if (l < 3) {
    unsigned long long O1 = 64ull * M;
    out[O1 + 3ull * m + l] = psum / (float)n;
  }
}

// ---- edges: fine-partition histogram (LDS-aggregated) ----
__global__ void __launch_bounds__(256) k_ehist2(const int2* __restrict__ ei,
                                                const unsigned* __restrict__ inv,
                                                unsigned* __restrict__ partCnt, int E, int span) {
  __shared__ unsigned h[NPART];
  for (int i = threadIdx.x; i < NPART; i += 256) h[i] = 0;
  __syncthreads();
  int lo = blockIdx.x * span;
  int hi = min(E, lo + span);
  for (int e = lo + threadIdx.x; e < hi; e += 256) {
    int2 pr = ei[e];
    unsigned a = inv[pr.x], b = inv[pr.y];
    if (a != b) atomicAdd(&h[a >> PSHIFT], 1u);
  }
  __syncthreads();
  for (int i = threadIdx.x; i < NPART; i += 256) {
    unsigned v = h[i];
    if (v) atomicAdd(&partCnt[i], v);
  }
}

// ---- edges pass 1: scatter into 64 coarse buckets; code32 = (srcLow13<<19)|dst.
//      Per-block runs ~120 edges = 480B -> no write amplification. ----
__global__ void __launch_bounds__(256) k_pscat1(const int2* __restrict__ ei,
                                                const unsigned* __restrict__ inv,
                                                unsigned* __restrict__ ccur,
                                                unsigned* __restrict__ stage1, int E) {
  __shared__ unsigned h[NCOARSE];
  if (threadIdx.x < NCOARSE) h[threadIdx.x] = 0;
  __syncthreads();
  int lo = blockIdx.x * (256 * PS_ITERS);
  unsigned long long codes[PS_ITERS];
#pragma unroll
  for (int it = 0; it < PS_ITERS; ++it) {
    codes[it] = ~0ull;
    int e = lo + threadIdx.x + it * 256;
    if (e < E) {
      int2 pr = ei[e];
      unsigned a = inv[pr.x], b = inv[pr.y];
      if (a != b) {
        codes[it] = ((unsigned long long)a << 19) | b;
        atomicAdd(&h[a >> CSHIFT], 1u);
      }
    }
  }
  __syncthreads();
  if (threadIdx.x < NCOARSE) {
    unsigned v = h[threadIdx.x];
    h[threadIdx.x] = v ? atomicAdd(&ccur[threadIdx.x], v) : 0u;
  }
  __syncthreads();
#pragma unroll
  for (int it = 0; it < PS_ITERS; ++it) {
    unsigned long long code = codes[it];
    if (code != ~0ull) {
      unsigned a = (unsigned)(code >> 19);
      unsigned off = atomicAdd(&h[a >> CSHIFT], 1u);
      stage1[off] = ((a & CMASK) << 19) | ((unsigned)code & 0x7FFFFu);
    }
  }
}

// ---- edges pass 2: coarse stream -> fine partitions (code27 into pStage).
//      Coarse bucket per element via LDS-cached boundary walk; a block's chunk
//      lies in ~1 coarse bucket -> per-partition runs ~128 edges = 512B. ----
__global__ void __launch_bounds__(256) k_pscat2(const unsigned* __restrict__ stage1,
                                                const unsigned* __restrict__ partStart,
                                                unsigned* __restrict__ partCursor,
                                                unsigned* __restrict__ pStage) {
  __shared__ unsigned h[NPART];
  __shared__ unsigned cbL[NCOARSE + 1];
  __shared__ unsigned c0s;
  for (int i = threadIdx.x; i < NPART; i += 256) h[i] = 0;
  if (threadIdx.x <= NCOARSE) cbL[threadIdx.x] = partStart[threadIdx.x << 5];
  __syncthreads();
  unsigned base = blockIdx.x * (256u * PS_ITERS);
  unsigned validE = cbL[NCOARSE];
  if (base >= validE) return;  // block-uniform exit
  if (threadIdx.x == 0) {
    unsigned c = 0;
    while (cbL[c + 1] <= base) ++c;
    c0s = c;
  }
  __syncthreads();
  unsigned codes[PS_ITERS], prt[PS_ITERS];
  unsigned c = c0s;
#pragma unroll
  for (int it = 0; it < PS_ITERS; ++it) {
    prt[it] = 0xFFFFFFFFu;
    unsigned g = base + threadIdx.x + it * 256u;
    if (g < validE) {
      while (cbL[c + 1] <= g) ++c;  // monotone in it
      unsigned code = stage1[g];
      codes[it] = code;
      unsigned part = (c << 5) | (code >> 27);
      prt[it] = part;
      atomicAdd(&h[part], 1u);
    }
  }
  __syncthreads();
  for (int i = threadIdx.x; i < NPART; i += 256) {
    unsigned v = h[i];
    h[i] = v ? atomicAdd(&partCursor[i], v) : 0u;
  }
  __syncthreads();
#pragma unroll
  for (int it = 0; it < PS_ITERS; ++it) {
    if (prt[it] != 0xFFFFFFFFu) {
      unsigned off = atomicAdd(&h[prt[it]], 1u);
      pStage[off] = codes[it] & 0x07FFFFFFu;
    }
  }
}

// ---- per-partition: LDS counting-sort by srcLow, element-parallel rank-sort by dst,
//      dedup flag + block-scan compaction. LDS ~19.5KB -> 8 blocks/CU. ----
__global__ void __launch_bounds__(256) k_bucket(unsigned* __restrict__ pStage,
                                                const unsigned* __restrict__ partStart,
                                                unsigned* __restrict__ partDistinct) {
  __shared__ unsigned dstL[SCAP2];
  __shared__ unsigned h[PB];
  __shared__ unsigned bbase[PB + 1];
  __shared__ unsigned stmp[256];
  unsigned p = blockIdx.x;
  unsigned s = partStart[p];
  unsigned c = partStart[p + 1] - s;
  unsigned t = threadIdx.x;
  h[t] = 0;  // PB == 256 == blockDim
  __syncthreads();
  if (c <= SCAP2) {
    const unsigned* src = pStage + s;
    // 1) histogram by srcLow
    for (unsigned i = t; i < c; i += 256) atomicAdd(&h[src[i] >> 19], 1u);
    __syncthreads();
    {  // 2) exclusive scan h -> bbase (256 entries, one per thread)
      unsigned v = h[t];
      stmp[t] = v;
      __syncthreads();
      for (int off = 1; off < 256; off <<= 1) {
        unsigned x = (t >= (unsigned)off) ? stmp[t - off] : 0u;
        __syncthreads(); stmp[t] += x; __syncthreads();
      }
      bbase[t] = stmp[t] - v;
      if (t == 255) bbase[PB] = stmp[255];
    }
    __syncthreads();
    h[t] = bbase[t];  // h becomes cursor
    __syncthreads();
    // 3) scatter code into bucket-contiguous LDS
    for (unsigned i = t; i < c; i += 256) {
      unsigned code = src[i];
      unsigned off = atomicAdd(&h[code >> 19], 1u);
      dstL[off] = code;
    }
    __syncthreads();
    // 4) element-parallel stable rank within bucket
    unsigned L = (c + 255) >> 8;  // elements per thread (blocked), <= 16
    unsigned vv[16], rr[16];
#pragma unroll
    for (unsigned k = 0; k < 16; ++k) {
      unsigned i = t * L + k;
      if (k < L && i < c) {
        unsigned v = dstL[i];
        unsigned b = v >> 19;
        unsigned blo = bbase[b], bhi = bbase[b + 1];
        unsigned r = blo;
        for (unsigned j = blo; j < bhi; ++j) {
          unsigned u = dstL[j];
          r += (u < v) || (u == v && j < i);
        }
        vv[k] = v; rr[k] = r;
      }
    }
    __syncthreads();
    // 5) in-place scatter to sorted position
#pragma unroll
    for (unsigned k = 0; k < 16; ++k) {
      unsigned i = t * L + k;
      if (k < L && i < c) dstL[rr[k]] = vv[k];
    }
    __syncthreads();
    // 6) dedup flags (partition now sorted by code) + block scan
    unsigned flm = 0, localSum = 0;
#pragma unroll
    for (unsigned k = 0; k < 16; ++k) {
      unsigned i = t * L + k;
      if (k < L && i < c) {
        unsigned v = dstL[i];
        unsigned pv = dstL[i - (i > 0 ? 1u : 0u)];
        unsigned f = (i == 0) | (pv != v);
        flm |= f << k;
        localSum += f;
      }
    }
    stmp[t] = localSum;
    __syncthreads();
    for (int off = 1; off < 256; off <<= 1) {
      unsigned x = (t >= (unsigned)off) ? stmp[t - off] : 0u;
      __syncthreads(); stmp[t] += x; __syncthreads();
    }
    unsigned pos = stmp[t] - localSum;
    // 7) compact distinct codes back to pStage (sorted by (src,dst))
#pragma unroll
    for (unsigned k = 0; k < 16; ++k) {
      unsigned i = t * L + k;
      if (k < L && i < c && ((flm >> k) & 1u)) {
        pStage[s + pos] = dstL[i];
        ++pos;
      }
    }
    if (t == 255) partDistinct[p] = stmp[255];
  } else if (t == 0) {  // fallback, statistically unreachable
    unsigned* a = pStage + s;
    for (unsigned i = 1; i < c; ++i) {
      unsigned v = a[i];
      long long j = (long long)i - 1;
      while (j >= 0 && a[j] > v) { a[j + 1] = a[j]; --j; }
      a[j + 1] = v;
    }
    unsigned d = 0, prev = 0xFFFFFFFFu;
    for (unsigned i = 0; i < c; ++i) {
      unsigned v = a[i];
      if (i == 0 || v != prev) { a[d] = v; ++d; }
      prev = v;
    }
    partDistinct[p] = d;
  }
}

// ---- write deduped edges (reconstruct src from partition id) ----
__global__ void __launch_bounds__(256) k_ewriteP(const unsigned* __restrict__ pStage,
                                                 const unsigned* __restrict__ partStart,
                                                 const unsigned* __restrict__ partOut,
                                                 const unsigned* __restrict__ hdr,
                                                 float* __restrict__ out) {
  unsigned p = blockIdx.x;
  unsigned s = partStart[p];
  unsigned rbase = partOut[p];
  unsigned d = partOut[p + 1] - rbase;
  unsigned M = hdr[3];
  unsigned long long O2 = 67ull * M;
  unsigned pbase = p << PSHIFT;
  for (unsigned j = threadIdx.x; j < d; j += 256) {
    unsigned code = pStage[s + j];
    unsigned long long row = (unsigned long long)rbase + j;
    out[O2 + 2 * row + 0] = (float)(pbase | (code >> 19));
    out[O2 + 2 * row + 1] = (float)(code & 0x7FFFFu);
  }
}

// ---- self loops + new_batch ----
__global__ void k_final(const unsigned* __restrict__ ukeyArr, const unsigned* __restrict__ hdr,
                        float* __restrict__ out) {
  unsigned m = blockIdx.x * blockDim.x + threadIdx.x;
  unsigned M = hdr[3];
  if (m >= M) return;
  unsigned Ed = hdr[5];
  unsigned long long O2 = 67ull * M;
  unsigned long long row = (unsigned long long)Ed + m;
  float fm = (float)m;
  out[O2 + 2 * row + 0] = fm;
  out[O2 + 2 * row + 1] = fm;
  unsigned long long O3 = O2 + 2ull * (Ed + M);
  out[O3 + m] = (float)(ukeyArr[m] >> 15);  // key / 32768 = batch id
}

extern "C" void kernel_launch(void* const* d_in, const int* in_sizes, int n_in,
                              void* d_out, int out_size, void* d_ws, size_t ws_size,
                              hipStream_t stream) {
  const float* x = (const float*)d_in[0];
  const float* pos = (const float*)d_in[1];
  const int* ei = (const int*)d_in[2];
  const int* batch = (const int*)d_in[3];
  float* out = (float*)d_out;
  int N = in_sizes[3];
  int E = in_sizes[2] / 2;

  unsigned* ws = (unsigned*)d_ws;
  // ws layout (u32 units)
  unsigned* hdr          = ws;                        // 64
  unsigned* cnt          = ws + 64;                   // KSP
  unsigned* partCnt      = cnt + KSP;                 // NPART
  unsigned* partDistinct = partCnt + NPART;           // NPART
  unsigned* rank         = partDistinct + NPART;      // KSP
  unsigned* ukeyArr      = rank + KSP;                // KSP
  unsigned* cStart       = ukeyArr + KSP;             // KSP+2 (M+1 used)
  unsigned* partStart    = cStart + KSP + 2;          // NPART+2
  unsigned* partCursor   = partStart + NPART + 2;     // NPART
  unsigned* partOut      = partCursor + NPART;        // NPART+2
  unsigned* chunkP       = partOut + NPART + 2;       // 1024 (NCHUNK used)
  unsigned* chunkC       = chunkP + 1024;             // 1024
  unsigned* ccur         = chunkC + 1024;             // 66 (coarse cursors)
  unsigned* key          = ccur + 66;                 // N
  unsigned* inv          = key + N;                   // N
  unsigned* pS32         = inv + ((N + 1) & ~1);      // 8B-aligned
  unsigned* pStage       = pS32;                      // E u32 (fine-sorted edge codes)
  unsigned* stage1       = pS32 + E;                  // E u32 (coarse-sorted code32)
  // scratch aliased into pStage region (dead before edge phase; stream-ordered):
  unsigned* ptStart  = pS32;                 // KSP (scan output; mutated to cursors)
  unsigned* ptOrder  = pS32 + KSP;           // N

  // zero: hdr + cnt + partCnt + partDistinct (contiguous).
  hipMemsetAsync(ws, 0, (size_t)(64 + KSP + 2 * NPART) * 4, stream);

  const int B = 256;
  int gN = (N + B - 1) / B;
  int gK = (KSP + B - 1) / B;
  int gP = (int)(((long long)N * 8 + B - 1) / B);  // k_pool: 8 lanes per voxel, M<=N
  int ebH = 2048;                                  // k_ehist2 blocks
  int spanH = (E + ebH - 1) / ebH;
  int ebS = (E + 256 * PS_ITERS - 1) / (256 * PS_ITERS);  // pscat1/pscat2 blocks

  k_keys<<<gN, B, 0, stream>>>(pos, batch, key, cnt, N);

  // fused dual scan: rank (presence) + ptStart (counts); hdr[3] = M
  scanA2<<<NCHUNK, SCAN_BLOCK, 0, stream>>>(cnt, rank, ptStart, chunkP, chunkC, KSP);
  scanB2<<<1, NCHUNK, 0, stream>>>(chunkP, chunkC, &hdr[3]);
  scanC2<<<gK, B, 0, stream>>>(rank, ptStart, chunkP, chunkC, KSP);

  k_ukey<<<gK, B, 0, stream>>>(cnt, rank, ptStart, hdr, ukeyArr, cStart, N);
  k_scatter<<<gN, B, 0, stream>>>(key, rank, inv, ptStart, ptOrder, N);
  k_pool<<<gP, B, 0, stream>>>((const float4*)x, pos, ptOrder, cStart, hdr, out);

  // edges: hist -> scan(+coarse cursors) -> coarse scatter -> fine scatter -> dedup -> write
  const int2* ei2 = (const int2*)ei;
  k_ehist2<<<ebH, 256, 0, stream>>>(ei2, inv, partCnt, E, spanH);
  k_scanP<<<1, 1024, 0, stream>>>(partCnt, partStart, partCursor, ccur, &hdr[4]);
  k_pscat1<<<ebS, 256, 0, stream>>>(ei2, inv, ccur, stage1, E);
  k_pscat2<<<ebS, 256, 0, stream>>>(stage1, partStart, partCursor, pStage);
  k_bucket<<<NPART, 256, 0, stream>>>(pStage, partStart, partDistinct);
  k_scanP<<<1, 1024, 0, stream>>>(partDistinct, partOut, nullptr, nullptr, &hdr[5]);
  k_ewriteP<<<NPART, 256, 0, stream>>>(pStage, partStart, partOut, hdr, out);
  k_final<<<gK, B, 0, stream>>>(ukeyArr, hdr, out);

  (void)n_in; (void)ws_size;
}

// Round 8
// 430.475 us; speedup vs baseline: 1.4765x; 1.0661x over previous
//
#include <hip/hip_runtime.h>

// GraphPooling: voxel-grid pooling.
//  inputs: x[N,64] f32, pos[N,3] f32, edge_index[E,2] i32, batch[N] i32
//  outputs (concat, f32): pooled_x[M,64], pos_mean[M,3], ei_out[Ed+M,2], new_batch[M]
// Keyspace: key = ((b*32+qx)*32+qy)*32+qz < 524288 (strides hardcoded: pos<128 so
// qpos<32; any stride >= max+1 preserves the lex order that defines rank order,
// and new_batch = key/32768 is exact).
// Pooling: voxel-sorted point permutation (ptOrder) + compact segment starts
// (cStart[m]) + 8-lanes-per-voxel segment reduce.
// Edge pipeline (two-level scatter, all store runs >= 0.5KB):
//   ehist: fine histogram, single gather (self-loops included: ~1e-5 of E;
//          they are filtered in k_bucket's dedup flag, where src is known).
//   pscat1: ei -> 64 coarse buckets (src>>13), code32=(srcLow13<<19)|dst
//   pscat2: coarse stream -> 2048 fine partitions (src>>8), code27
//   k_bucket: LDS counting-sort by srcLow8 + element-parallel rank-sort by dst,
//   dedup+selfloop flag + block-scan compaction.

#define KSP 524288
#define SCAN_BLOCK 256
#define SCAN_ITEMS 16
#define SCAN_CHUNK 4096            // SCAN_BLOCK * SCAN_ITEMS
#define NCHUNK (KSP / SCAN_CHUNK)  // 128
#define NPART 2048
#define PSHIFT 8                   // partition = src >> PSHIFT
#define PB 256                     // voxel ranks per partition (KSP/NPART)
#define SCAP2 4096                 // LDS cap: edges per partition (mean ~2.9k)
#define NCOARSE 64
#define CSHIFT 13                  // coarse bucket = src >> CSHIFT
#define CMASK 8191u
#define PS_ITERS 16                // edges per thread in ehist/pscat1/pscat2

// ws header slots (u32): [3]=M, [4]=stagedE, [5]=Ed

// ---- per-point: voxel key + histogram (strides hardcoded to 32) ----
__global__ void k_keys(const float* __restrict__ pos, const int* __restrict__ batch,
                       unsigned* __restrict__ key, unsigned* __restrict__ cnt, int N) {
  int i = blockIdx.x * blockDim.x + threadIdx.x;
  if (i >= N) return;
  unsigned q0 = (unsigned)(int)floorf(pos[3 * i + 0] * 0.25f);
  unsigned q1 = (unsigned)(int)floorf(pos[3 * i + 1] * 0.25f);
  unsigned q2 = (unsigned)(int)floorf(pos[3 * i + 2] * 0.25f);
  unsigned k = ((((((unsigned)batch[i] << 5) | q0) << 5) | q1) << 5) | q2;
  key[i] = k;
  atomicAdd(&cnt[k], 1u);
}

// ---- fused dual exclusive scan over KSP: presence(cnt) -> rank, cnt -> ptStart ----
__global__ void scanA2(const unsigned* __restrict__ in, unsigned* __restrict__ outRank,
                       unsigned* __restrict__ outStart, unsigned* __restrict__ chunkP,
                       unsigned* __restrict__ chunkC, int n) {
  __shared__ unsigned ldsP[SCAN_BLOCK];
  __shared__ unsigned ldsC[SCAN_BLOCK];
  int tbase = blockIdx.x * SCAN_CHUNK + threadIdx.x * SCAN_ITEMS;
  unsigned valsP[SCAN_ITEMS], valsC[SCAN_ITEMS];
  unsigned sp = 0, sc = 0;
  for (int i = 0; i < SCAN_ITEMS; ++i) {
    unsigned v = 0;
    int idx = tbase + i;
    if (idx < n) v = in[idx];
    valsP[i] = sp; valsC[i] = sc;
    sp += v ? 1u : 0u;
    sc += v;
  }
  ldsP[threadIdx.x] = sp; ldsC[threadIdx.x] = sc;
  __syncthreads();
  for (int off = 1; off < SCAN_BLOCK; off <<= 1) {
    unsigned tp = (threadIdx.x >= (unsigned)off) ? ldsP[threadIdx.x - off] : 0u;
    unsigned tc = (threadIdx.x >= (unsigned)off) ? ldsC[threadIdx.x - off] : 0u;
    __syncthreads();
    ldsP[threadIdx.x] += tp; ldsC[threadIdx.x] += tc;
    __syncthreads();
  }
  unsigned exP = ldsP[threadIdx.x] - sp;
  unsigned exC = ldsC[threadIdx.x] - sc;
  for (int i = 0; i < SCAN_ITEMS; ++i) {
    int idx = tbase + i;
    if (idx < n) { outRank[idx] = exP + valsP[i]; outStart[idx] = exC + valsC[i]; }
  }
  if (threadIdx.x == SCAN_BLOCK - 1) {
    chunkP[blockIdx.x] = ldsP[SCAN_BLOCK - 1];
    chunkC[blockIdx.x] = ldsC[SCAN_BLOCK - 1];
  }
}

__global__ void scanB2(unsigned* chunkP, unsigned* chunkC, unsigned* mDst) {
  __shared__ unsigned lp[NCHUNK];
  __shared__ unsigned lc[NCHUNK];
  unsigned t = threadIdx.x;  // NCHUNK threads
  unsigned vp = chunkP[t], vc = chunkC[t];
  lp[t] = vp; lc[t] = vc;
  __syncthreads();
  for (int off = 1; off < NCHUNK; off <<= 1) {
    unsigned xp = (t >= (unsigned)off) ? lp[t - off] : 0u;
    unsigned xc = (t >= (unsigned)off) ? lc[t - off] : 0u;
    __syncthreads();
    lp[t] += xp; lc[t] += xc;
    __syncthreads();
  }
  chunkP[t] = lp[t] - vp;
  chunkC[t] = lc[t] - vc;
  if (t == NCHUNK - 1 && mDst) *mDst = lp[NCHUNK - 1];
}

__global__ void scanC2(unsigned* __restrict__ rank, unsigned* __restrict__ ptStart,
                       const unsigned* __restrict__ chunkP, const unsigned* __restrict__ chunkC,
                       int n) {
  int idx = blockIdx.x * blockDim.x + threadIdx.x;
  if (idx >= n) return;
  int ch = idx / SCAN_CHUNK;
  rank[idx] += chunkP[ch];
  ptStart[idx] += chunkC[ch];
}

// ---- single-block exclusive scan of NPART entries (1024 thr x 2 items).
//      Also seeds the 64 coarse-bucket cursors (ccur[c] = excl at index 32c). ----
__global__ void k_scanP(const unsigned* __restrict__ in, unsigned* __restrict__ outStart,
                        unsigned* __restrict__ outCursor, unsigned* __restrict__ ccur,
                        unsigned* __restrict__ totalDst) {
  __shared__ unsigned lds[1024];
  unsigned t = threadIdx.x;
  unsigned a = in[2 * t], b = in[2 * t + 1];
  unsigned sum = a + b;
  lds[t] = sum;
  __syncthreads();
  for (int off = 1; off < 1024; off <<= 1) {
    unsigned x = (t >= (unsigned)off) ? lds[t - off] : 0u;
    __syncthreads();
    lds[t] += x;
    __syncthreads();
  }
  unsigned excl = lds[t] - sum;
  outStart[2 * t] = excl;
  outStart[2 * t + 1] = excl + a;
  if (outCursor) { outCursor[2 * t] = excl; outCursor[2 * t + 1] = excl + a; }
  if (ccur && (t & 15u) == 0) ccur[t >> 4] = excl;  // index 2t ≡ 0 mod 32
  if (t == 1023) {
    outStart[NPART] = lds[1023];
    if (totalDst) *totalDst = lds[1023];
  }
}

// ---- rank -> key map + compact segment starts (before k_scatter mutates ptStart) ----
__global__ void k_ukey(const unsigned* __restrict__ cnt, const unsigned* __restrict__ rank,
                       const unsigned* __restrict__ ptStart, const unsigned* __restrict__ hdr,
                       unsigned* __restrict__ ukeyArr, unsigned* __restrict__ cStart, int N) {
  int k = blockIdx.x * blockDim.x + threadIdx.x;
  if (k >= KSP) return;
  if (cnt[k]) {
    unsigned r = rank[k];
    ukeyArr[r] = (unsigned)k;
    cStart[r] = ptStart[k];
  }
  if (k == 0) cStart[hdr[3]] = (unsigned)N;
}

// ---- per-point: inv index + voxel-sorted permutation (ptStart doubles as cursor) ----
__global__ void k_scatter(const unsigned* __restrict__ key, const unsigned* __restrict__ rank,
                          unsigned* __restrict__ inv, unsigned* __restrict__ ptStart,
                          unsigned* __restrict__ ptOrder, int N) {
  int i = blockIdx.x * blockDim.x + threadIdx.x;
  if (i >= N) return;
  unsigned k = key[i];
  inv[i] = rank[k];
  unsigned posn = atomicAdd(&ptStart[k], 1u);
  ptOrder[posn] = (unsigned)i;
}

// ---- 8 lanes per voxel: feature max (2x float4 per lane = full 256B row) + pos mean ----
__global__ void __launch_bounds__(256) k_pool(const float4* __restrict__ x4,
                                              const float* __restrict__ pos,
                                              const unsigned* __restrict__ ptOrder,
                                              const unsigned* __restrict__ cStart,
                                              const unsigned* __restrict__ hdr,
                                              float* __restrict__ out) {
  unsigned gtid = blockIdx.x * blockDim.x + threadIdx.x;
  unsigned m = gtid >> 3;     // voxel id
  unsigned l = gtid & 7u;     // lane-in-group
  unsigned M = hdr[3];
  if (m >= M) return;
  unsigned start = cStart[m];
  unsigned n = cStart[m + 1] - start;
  const float NI = -__builtin_huge_valf();
  float4 a0 = make_float4(NI, NI, NI, NI);
  float4 a1 = a0;
  float psum = 0.0f;
  for (unsigned j = 0; j < n; ++j) {
    unsigned p = ptOrder[start + j];
    float4 v0 = x4[p * 16u + l];
    float4 v1 = x4[p * 16u + 8u + l];
    a0.x = fmaxf(a0.x, v0.x); a0.y = fmaxf(a0.y, v0.y);
    a0.z = fmaxf(a0.z, v0.z); a0.w = fmaxf(a0.w, v0.w);
    a1.x = fmaxf(a1.x, v1.x); a1.y = fmaxf(a1.y, v1.y);
    a1.z = fmaxf(a1.z, v1.z); a1.w = fmaxf(a1.w, v1.w);
    if (l < 3) psum += pos[3u * p + l];
  }
  float4* o4 = (float4*)out;
  o4[m * 16u + l] = a0;
  o4[m * 16u + 8u + l] = a1;
  if (l < 3) {
    unsigned long long O1 = 64ull * M;
    out[O1 + 3ull * m + l] = psum / (float)n;
  }
}

// ---- edges: fine-partition histogram; SINGLE gather (src only), register-batched
//      for deep MLP. Self-loops counted (filtered later in k_bucket). ----
__global__ void __launch_bounds__(256) k_ehist(const int2* __restrict__ ei,
                                               const unsigned* __restrict__ inv,
                                               unsigned* __restrict__ partCnt, int E) {
  __shared__ unsigned h[NPART];
  for (int i = threadIdx.x; i < NPART; i += 256) h[i] = 0;
  __syncthreads();
  int lo = blockIdx.x * (256 * PS_ITERS);
  unsigned av[PS_ITERS];
#pragma unroll
  for (int it = 0; it < PS_ITERS; ++it) {
    int e = lo + threadIdx.x + it * 256;
    av[it] = (e < E) ? (unsigned)ei[e].x : 0xFFFFFFFFu;
  }
#pragma unroll
  for (int it = 0; it < PS_ITERS; ++it) {
    if (av[it] != 0xFFFFFFFFu) av[it] = inv[av[it]];
  }
#pragma unroll
  for (int it = 0; it < PS_ITERS; ++it) {
    if (av[it] != 0xFFFFFFFFu) atomicAdd(&h[av[it] >> PSHIFT], 1u);
  }
  __syncthreads();
  for (int i = threadIdx.x; i < NPART; i += 256) {
    unsigned v = h[i];
    if (v) atomicAdd(&partCnt[i], v);
  }
}

// ---- edges pass 1: scatter into 64 coarse buckets; code32 = (srcLow13<<19)|dst.
//      Self-loops staged too (negligible count; filtered in k_bucket). ----
__global__ void __launch_bounds__(256) k_pscat1(const int2* __restrict__ ei,
                                                const unsigned* __restrict__ inv,
                                                unsigned* __restrict__ ccur,
                                                unsigned* __restrict__ stage1, int E) {
  __shared__ unsigned h[NCOARSE];
  if (threadIdx.x < NCOARSE) h[threadIdx.x] = 0;
  __syncthreads();
  int lo = blockIdx.x * (256 * PS_ITERS);
  unsigned long long codes[PS_ITERS];
#pragma unroll
  for (int it = 0; it < PS_ITERS; ++it) {
    codes[it] = ~0ull;
    int e = lo + threadIdx.x + it * 256;
    if (e < E) {
      int2 pr = ei[e];
      unsigned a = inv[pr.x], b = inv[pr.y];
      codes[it] = ((unsigned long long)a << 19) | b;
      atomicAdd(&h[a >> CSHIFT], 1u);
    }
  }
  __syncthreads();
  if (threadIdx.x < NCOARSE) {
    unsigned v = h[threadIdx.x];
    h[threadIdx.x] = v ? atomicAdd(&ccur[threadIdx.x], v) : 0u;
  }
  __syncthreads();
#pragma unroll
  for (int it = 0; it < PS_ITERS; ++it) {
    unsigned long long code = codes[it];
    if (code != ~0ull) {
      unsigned a = (unsigned)(code >> 19);
      unsigned off = atomicAdd(&h[a >> CSHIFT], 1u);
      stage1[off] = ((a & CMASK) << 19) | ((unsigned)code & 0x7FFFFu);
    }
  }
}

// ---- edges pass 2: coarse stream -> fine partitions (code27 into pStage). ----
__global__ void __launch_bounds__(256) k_pscat2(const unsigned* __restrict__ stage1,
                                                const unsigned* __restrict__ partStart,
                                                unsigned* __restrict__ partCursor,
                                                unsigned* __restrict__ pStage) {
  __shared__ unsigned h[NPART];
  __shared__ unsigned cbL[NCOARSE + 1];
  __shared__ unsigned c0s;
  for (int i = threadIdx.x; i < NPART; i += 256) h[i] = 0;
  if (threadIdx.x <= NCOARSE) cbL[threadIdx.x] = partStart[threadIdx.x << 5];
  __syncthreads();
  unsigned base = blockIdx.x * (256u * PS_ITERS);
  unsigned validE = cbL[NCOARSE];
  if (base >= validE) return;  // block-uniform exit
  if (threadIdx.x == 0) {
    unsigned c = 0;
    while (cbL[c + 1] <= base) ++c;
    c0s = c;
  }
  __syncthreads();
  unsigned codes[PS_ITERS], prt[PS_ITERS];
  unsigned c = c0s;
#pragma unroll
  for (int it = 0; it < PS_ITERS; ++it) {
    prt[it] = 0xFFFFFFFFu;
    unsigned g = base + threadIdx.x + it * 256u;
    if (g < validE) {
      while (cbL[c + 1] <= g) ++c;  // monotone in it
      unsigned code = stage1[g];
      codes[it] = code;
      unsigned part = (c << 5) | (code >> 27);
      prt[it] = part;
      atomicAdd(&h[part], 1u);
    }
  }
  __syncthreads();
  for (int i = threadIdx.x; i < NPART; i += 256) {
    unsigned v = h[i];
    h[i] = v ? atomicAdd(&partCursor[i], v) : 0u;
  }
  __syncthreads();
#pragma unroll
  for (int it = 0; it < PS_ITERS; ++it) {
    if (prt[it] != 0xFFFFFFFFu) {
      unsigned off = atomicAdd(&h[prt[it]], 1u);
      pStage[off] = codes[it] & 0x07FFFFFFu;
    }
  }
}

// ---- per-partition: LDS counting-sort by srcLow, element-parallel rank-sort by dst,
//      dedup+selfloop flag + block-scan compaction. LDS ~19.5KB -> 8 blocks/CU. ----
__global__ void __launch_bounds__(256) k_bucket(unsigned* __restrict__ pStage,
                                                const unsigned* __restrict__ partStart,
                                                unsigned* __restrict__ partDistinct) {
  __shared__ unsigned dstL[SCAP2];
  __shared__ unsigned h[PB];
  __shared__ unsigned bbase[PB + 1];
  __shared__ unsigned stmp[256];
  unsigned p = blockIdx.x;
  unsigned s = partStart[p];
  unsigned c = partStart[p + 1] - s;
  unsigned t = threadIdx.x;
  unsigned pb = p << PSHIFT;  // absolute src base of this partition
  h[t] = 0;  // PB == 256 == blockDim
  __syncthreads();
  if (c <= SCAP2) {
    const unsigned* src = pStage + s;
    // 1) histogram by srcLow
    for (unsigned i = t; i < c; i += 256) atomicAdd(&h[src[i] >> 19], 1u);
    __syncthreads();
    {  // 2) exclusive scan h -> bbase (256 entries, one per thread)
      unsigned v = h[t];
      stmp[t] = v;
      __syncthreads();
      for (int off = 1; off < 256; off <<= 1) {
        unsigned x = (t >= (unsigned)off) ? stmp[t - off] : 0u;
        __syncthreads(); stmp[t] += x; __syncthreads();
      }
      bbase[t] = stmp[t] - v;
      if (t == 255) bbase[PB] = stmp[255];
    }
    __syncthreads();
    h[t] = bbase[t];  // h becomes cursor
    __syncthreads();
    // 3) scatter code into bucket-contiguous LDS
    for (unsigned i = t; i < c; i += 256) {
      unsigned code = src[i];
      unsigned off = atomicAdd(&h[code >> 19], 1u);
      dstL[off] = code;
    }
    __syncthreads();
    // 4) element-parallel stable rank within bucket
    unsigned L = (c + 255) >> 8;  // elements per thread (blocked), <= 16
    unsigned vv[16], rr[16];
#pragma unroll
    for (unsigned k = 0; k < 16; ++k) {
      unsigned i = t * L + k;
      if (k < L && i < c) {
        unsigned v = dstL[i];
        unsigned b = v >> 19;
        unsigned blo = bbase[b], bhi = bbase[b + 1];
        unsigned r = blo;
        for (unsigned j = blo; j < bhi; ++j) {
          unsigned u = dstL[j];
          r += (u < v) || (u == v && j < i);
        }
        vv[k] = v; rr[k] = r;
      }
    }
    __syncthreads();
    // 5) in-place scatter to sorted position
#pragma unroll
    for (unsigned k = 0; k < 16; ++k) {
      unsigned i = t * L + k;
      if (k < L && i < c) dstL[rr[k]] = vv[k];
    }
    __syncthreads();
    // 6) dedup + self-loop flags (partition now sorted by code) + block scan
    unsigned flm = 0, localSum = 0;
#pragma unroll
    for (unsigned k = 0; k < 16; ++k) {
      unsigned i = t * L + k;
      if (k < L && i < c) {
        unsigned v = dstL[i];
        unsigned pv = dstL[i - (i > 0 ? 1u : 0u)];
        unsigned notself = ((v & 0x7FFFFu) != (pb | (v >> 19))) ? 1u : 0u;
        unsigned f = (((i == 0) | (pv != v)) ? 1u : 0u) & notself;
        flm |= f << k;
        localSum += f;
      }
    }
    stmp[t] = localSum;
    __syncthreads();
    for (int off = 1; off < 256; off <<= 1) {
      unsigned x = (t >= (unsigned)off) ? stmp[t - off] : 0u;
      __syncthreads(); stmp[t] += x; __syncthreads();
    }
    unsigned pos = stmp[t] - localSum;
    // 7) compact distinct codes back to pStage (sorted by (src,dst))
#pragma unroll
    for (unsigned k = 0; k < 16; ++k) {
      unsigned i = t * L + k;
      if (k < L && i < c && ((flm >> k) & 1u)) {
        pStage[s + pos] = dstL[i];
        ++pos;
      }
    }
    if (t == 255) partDistinct[p] = stmp[255];
  } else if (t == 0) {  // fallback, statistically unreachable
    unsigned* a = pStage + s;
    for (unsigned i = 1; i < c; ++i) {
      unsigned v = a[i];
      long long j = (long long)i - 1;
      while (j >= 0 && a[j] > v) { a[j + 1] = a[j]; --j; }
      a[j + 1] = v;
    }
    unsigned d = 0, prev = 0xFFFFFFFFu;
    for (unsigned i = 0; i < c; ++i) {
      unsigned v = a[i];
      if ((i == 0 || v != prev) && ((v & 0x7FFFFu) != (pb | (v >> 19)))) { a[d] = v; ++d; }
      prev = v;
    }
    partDistinct[p] = d;
  }
}

// ---- write deduped edges (reconstruct src from partition id) ----
__global__ void __launch_bounds__(256) k_ewriteP(const unsigned* __restrict__ pStage,
                                                 const unsigned* __restrict__ partStart,
                                                 const unsigned* __restrict__ partOut,
                                                 const unsigned* __restrict__ hdr,
                                                 float* __restrict__ out) {
  unsigned p = blockIdx.x;
  unsigned s = partStart[p];
  unsigned rbase = partOut[p];
  unsigned d = partOut[p + 1] - rbase;
  unsigned M = hdr[3];
  unsigned long long O2 = 67ull * M;
  unsigned pbase = p << PSHIFT;
  for (unsigned j = threadIdx.x; j < d; j += 256) {
    unsigned code = pStage[s + j];
    unsigned long long row = (unsigned long long)rbase + j;
    out[O2 + 2 * row + 0] = (float)(pbase | (code >> 19));
    out[O2 + 2 * row + 1] = (float)(code & 0x7FFFFu);
  }
}

// ---- self loops + new_batch ----
__global__ void k_final(const unsigned* __restrict__ ukeyArr, const unsigned* __restrict__ hdr,
                        float* __restrict__ out) {
  unsigned m = blockIdx.x * blockDim.x + threadIdx.x;
  unsigned M = hdr[3];
  if (m >= M) return;
  unsigned Ed = hdr[5];
  unsigned long long O2 = 67ull * M;
  unsigned long long row = (unsigned long long)Ed + m;
  float fm = (float)m;
  out[O2 + 2 * row + 0] = fm;
  out[O2 + 2 * row + 1] = fm;
  unsigned long long O3 = O2 + 2ull * (Ed + M);
  out[O3 + m] = (float)(ukeyArr[m] >> 15);  // key / 32768 = batch id
}

extern "C" void kernel_launch(void* const* d_in, const int* in_sizes, int n_in,
                              void* d_out, int out_size, void* d_ws, size_t ws_size,
                              hipStream_t stream) {
  const float* x = (const float*)d_in[0];
  const float* pos = (const float*)d_in[1];
  const int* ei = (const int*)d_in[2];
  const int* batch = (const int*)d_in[3];
  float* out = (float*)d_out;
  int N = in_sizes[3];
  int E = in_sizes[2] / 2;

  unsigned* ws = (unsigned*)d_ws;
  // ws layout (u32 units)
  unsigned* hdr          = ws;                        // 64
  unsigned* cnt          = ws + 64;                   // KSP
  unsigned* partCnt      = cnt + KSP;                 // NPART
  unsigned* partDistinct = partCnt + NPART;           // NPART
  unsigned* rank         = partDistinct + NPART;      // KSP
  unsigned* ukeyArr      = rank + KSP;                // KSP
  unsigned* cStart       = ukeyArr + KSP;             // KSP+2 (M+1 used)
  unsigned* partStart    = cStart + KSP + 2;          // NPART+2
  unsigned* partCursor   = partStart + NPART + 2;     // NPART
  unsigned* partOut      = partCursor + NPART;        // NPART+2
  unsigned* chunkP       = partOut + NPART + 2;       // 1024 (NCHUNK used)
  unsigned* chunkC       = chunkP + 1024;             // 1024
  unsigned* ccur         = chunkC + 1024;             // 66 (coarse cursors)
  unsigned* key          = ccur + 66;                 // N
  unsigned* inv          = key + N;                   // N
  unsigned* pS32         = inv + ((N + 1) & ~1);      // 8B-aligned
  unsigned* pStage       = pS32;                      // E u32 (fine-sorted edge codes)
  unsigned* stage1       = pS32 + E;                  // E u32 (coarse-sorted code32)
  // scratch aliased into pStage region (dead before edge phase; stream-ordered):
  unsigned* ptStart  = pS32;                 // KSP (scan output; mutated to cursors)
  unsigned* ptOrder  = pS32 + KSP;           // N

  // zero: hdr + cnt + partCnt + partDistinct (contiguous).
  hipMemsetAsync(ws, 0, (size_t)(64 + KSP + 2 * NPART) * 4, stream);

  const int B = 256;
  int gN = (N + B - 1) / B;
  int gK = (KSP + B - 1) / B;
  int gP = (int)(((long long)N * 8 + B - 1) / B);  // k_pool: 8 lanes per voxel, M<=N
  int ebS = (E + 256 * PS_ITERS - 1) / (256 * PS_ITERS);  // ehist/pscat1/pscat2 blocks

  k_keys<<<gN, B, 0, stream>>>(pos, batch, key, cnt, N);

  // fused dual scan: rank (presence) + ptStart (counts); hdr[3] = M
  scanA2<<<NCHUNK, SCAN_BLOCK, 0, stream>>>(cnt, rank, ptStart, chunkP, chunkC, KSP);
  scanB2<<<1, NCHUNK, 0, stream>>>(chunkP, chunkC, &hdr[3]);
  scanC2<<<gK, B, 0, stream>>>(rank, ptStart, chunkP, chunkC, KSP);

  k_ukey<<<gK, B, 0, stream>>>(cnt, rank, ptStart, hdr, ukeyArr, cStart, N);
  k_scatter<<<gN, B, 0, stream>>>(key, rank, inv, ptStart, ptOrder, N);
  k_pool<<<gP, B, 0, stream>>>((const float4*)x, pos, ptOrder, cStart, hdr, out);

  // edges: hist -> scan(+coarse cursors) -> coarse scatter -> fine scatter -> dedup -> write
  const int2* ei2 = (const int2*)ei;
  k_ehist<<<ebS, 256, 0, stream>>>(ei2, inv, partCnt, E);
  k_scanP<<<1, 1024, 0, stream>>>(partCnt, partStart, partCursor, ccur, &hdr[4]);
  k_pscat1<<<ebS, 256, 0, stream>>>(ei2, inv, ccur, stage1, E);
  k_pscat2<<<ebS, 256, 0, stream>>>(stage1, partStart, partCursor, pStage);
  k_bucket<<<NPART, 256, 0, stream>>>(pStage, partStart, partDistinct);
  k_scanP<<<1, 1024, 0, stream>>>(partDistinct, partOut, nullptr, nullptr, &hdr[5]);
  k_ewriteP<<<NPART, 256, 0, stream>>>(pStage, partStart, partOut, hdr, out);
  k_final<<<gK, B, 0, stream>>>(ukeyArr, hdr, out);

  (void)n_in; (void)ws_size;
}

// Round 9
// 427.106 us; speedup vs baseline: 1.4882x; 1.0079x over previous
//
#include <hip/hip_runtime.h>

// GraphPooling: voxel-grid pooling.
//  inputs: x[N,64] f32, pos[N,3] f32, edge_index[E,2] i32, batch[N] i32
//  outputs (concat, f32): pooled_x[M,64], pos_mean[M,3], ei_out[Ed+M,2], new_batch[M]
// Keyspace: key = ((b*32+qx)*32+qy)*32+qz < 524288 (strides hardcoded: pos<128 so
// qpos<32; any stride >= max+1 preserves the lex order that defines rank order,
// and new_batch = key/32768 is exact).
// Pooling: voxel-sorted point permutation (ptOrder) + compact segment starts
// (cStart[m], emitted by the fused scanC2) + 8-lanes-per-voxel segment reduce.
// Edge pipeline (two-level scatter, all store runs >= 0.5KB):
//   ehist: fine histogram + encode stage0[e]=(inv[src]<<19)|inv[dst] (u64, coalesced).
//   pscat1: stage0 (linear) -> 64 coarse buckets (src>>13), code32=(srcLow13<<19)|dst
//   pscat2: coarse stream -> 2048 fine partitions (src>>8), code27
//   k_bucket: LDS counting-sort by srcLow8 + element-parallel rank-sort by dst,
//   dedup+selfloop flag + block-scan compaction (self-loops staged, filtered here).
// Aliasing (stream-ordered): ptStart/ptOrder & later stage0 & later pStage share
// the region at pS32; stage1 sits at pS32+2E.

#define KSP 524288
#define SCAN_BLOCK 256
#define SCAN_ITEMS 16
#define SCAN_CHUNK 4096            // SCAN_BLOCK * SCAN_ITEMS
#define NCHUNK (KSP / SCAN_CHUNK)  // 128
#define NPART 2048
#define PSHIFT 8                   // partition = src >> PSHIFT
#define PB 256                     // voxel ranks per partition (KSP/NPART)
#define SCAP2 4096                 // LDS cap: edges per partition (mean ~2.9k)
#define NCOARSE 64
#define CSHIFT 13                  // coarse bucket = src >> CSHIFT
#define CMASK 8191u
#define PS_ITERS 16                // edges per thread in ehist/pscat1/pscat2
#define SC_ITERS 8                 // points per thread in k_scatter

// ws header slots (u32): [3]=M, [4]=stagedE, [5]=Ed

// ---- per-point: voxel key + histogram (strides hardcoded to 32) ----
__global__ void k_keys(const float* __restrict__ pos, const int* __restrict__ batch,
                       unsigned* __restrict__ key, unsigned* __restrict__ cnt, int N) {
  int i = blockIdx.x * blockDim.x + threadIdx.x;
  if (i >= N) return;
  unsigned q0 = (unsigned)(int)floorf(pos[3 * i + 0] * 0.25f);
  unsigned q1 = (unsigned)(int)floorf(pos[3 * i + 1] * 0.25f);
  unsigned q2 = (unsigned)(int)floorf(pos[3 * i + 2] * 0.25f);
  unsigned k = ((((((unsigned)batch[i] << 5) | q0) << 5) | q1) << 5) | q2;
  key[i] = k;
  atomicAdd(&cnt[k], 1u);
}

// ---- fused dual exclusive scan over KSP: presence(cnt) -> rank, cnt -> ptStart ----
__global__ void scanA2(const unsigned* __restrict__ in, unsigned* __restrict__ outRank,
                       unsigned* __restrict__ outStart, unsigned* __restrict__ chunkP,
                       unsigned* __restrict__ chunkC, int n) {
  __shared__ unsigned ldsP[SCAN_BLOCK];
  __shared__ unsigned ldsC[SCAN_BLOCK];
  int tbase = blockIdx.x * SCAN_CHUNK + threadIdx.x * SCAN_ITEMS;
  unsigned valsP[SCAN_ITEMS], valsC[SCAN_ITEMS];
  unsigned sp = 0, sc = 0;
  for (int i = 0; i < SCAN_ITEMS; ++i) {
    unsigned v = 0;
    int idx = tbase + i;
    if (idx < n) v = in[idx];
    valsP[i] = sp; valsC[i] = sc;
    sp += v ? 1u : 0u;
    sc += v;
  }
  ldsP[threadIdx.x] = sp; ldsC[threadIdx.x] = sc;
  __syncthreads();
  for (int off = 1; off < SCAN_BLOCK; off <<= 1) {
    unsigned tp = (threadIdx.x >= (unsigned)off) ? ldsP[threadIdx.x - off] : 0u;
    unsigned tc = (threadIdx.x >= (unsigned)off) ? ldsC[threadIdx.x - off] : 0u;
    __syncthreads();
    ldsP[threadIdx.x] += tp; ldsC[threadIdx.x] += tc;
    __syncthreads();
  }
  unsigned exP = ldsP[threadIdx.x] - sp;
  unsigned exC = ldsC[threadIdx.x] - sc;
  for (int i = 0; i < SCAN_ITEMS; ++i) {
    int idx = tbase + i;
    if (idx < n) { outRank[idx] = exP + valsP[i]; outStart[idx] = exC + valsC[i]; }
  }
  if (threadIdx.x == SCAN_BLOCK - 1) {
    chunkP[blockIdx.x] = ldsP[SCAN_BLOCK - 1];
    chunkC[blockIdx.x] = ldsC[SCAN_BLOCK - 1];
  }
}

__global__ void scanB2(unsigned* chunkP, unsigned* chunkC, unsigned* mDst) {
  __shared__ unsigned lp[NCHUNK];
  __shared__ unsigned lc[NCHUNK];
  unsigned t = threadIdx.x;  // NCHUNK threads
  unsigned vp = chunkP[t], vc = chunkC[t];
  lp[t] = vp; lc[t] = vc;
  __syncthreads();
  for (int off = 1; off < NCHUNK; off <<= 1) {
    unsigned xp = (t >= (unsigned)off) ? lp[t - off] : 0u;
    unsigned xc = (t >= (unsigned)off) ? lc[t - off] : 0u;
    __syncthreads();
    lp[t] += xp; lc[t] += xc;
    __syncthreads();
  }
  chunkP[t] = lp[t] - vp;
  chunkC[t] = lc[t] - vc;
  if (t == NCHUNK - 1 && mDst) *mDst = lp[NCHUNK - 1];
}

// ---- scanC2 fused with k_ukey: finalize rank/ptStart AND emit ukeyArr/cStart ----
__global__ void scanC2(unsigned* __restrict__ rank, unsigned* __restrict__ ptStart,
                       const unsigned* __restrict__ chunkP, const unsigned* __restrict__ chunkC,
                       const unsigned* __restrict__ cnt, const unsigned* __restrict__ hdr,
                       unsigned* __restrict__ ukeyArr, unsigned* __restrict__ cStart,
                       int n, int N) {
  int idx = blockIdx.x * blockDim.x + threadIdx.x;
  if (idx >= n) return;
  int ch = idx / SCAN_CHUNK;
  unsigned r = rank[idx] + chunkP[ch];
  unsigned s = ptStart[idx] + chunkC[ch];
  rank[idx] = r;
  ptStart[idx] = s;
  if (cnt[idx]) {
    ukeyArr[r] = (unsigned)idx;
    cStart[r] = s;
  }
  if (idx == 0) cStart[hdr[3]] = (unsigned)N;
}

// ---- single-block exclusive scan of NPART entries (1024 thr x 2 items).
//      Also seeds the 64 coarse-bucket cursors (ccur[c] = excl at index 32c). ----
__global__ void k_scanP(const unsigned* __restrict__ in, unsigned* __restrict__ outStart,
                        unsigned* __restrict__ outCursor, unsigned* __restrict__ ccur,
                        unsigned* __restrict__ totalDst) {
  __shared__ unsigned lds[1024];
  unsigned t = threadIdx.x;
  unsigned a = in[2 * t], b = in[2 * t + 1];
  unsigned sum = a + b;
  lds[t] = sum;
  __syncthreads();
  for (int off = 1; off < 1024; off <<= 1) {
    unsigned x = (t >= (unsigned)off) ? lds[t - off] : 0u;
    __syncthreads();
    lds[t] += x;
    __syncthreads();
  }
  unsigned excl = lds[t] - sum;
  outStart[2 * t] = excl;
  outStart[2 * t + 1] = excl + a;
  if (outCursor) { outCursor[2 * t] = excl; outCursor[2 * t + 1] = excl + a; }
  if (ccur && (t & 15u) == 0) ccur[t >> 4] = excl;  // index 2t ≡ 0 mod 32
  if (t == 1023) {
    outStart[NPART] = lds[1023];
    if (totalDst) *totalDst = lds[1023];
  }
}

// ---- per-point: inv index + voxel-sorted permutation; register-batched
//      (8 independent key->gather->atomic chains per thread) ----
__global__ void __launch_bounds__(256) k_scatter(const unsigned* __restrict__ key,
                                                 const unsigned* __restrict__ rank,
                                                 unsigned* __restrict__ inv,
                                                 unsigned* __restrict__ ptStart,
                                                 unsigned* __restrict__ ptOrder, int N) {
  int lo = blockIdx.x * (256 * SC_ITERS);
  unsigned kk[SC_ITERS], rv[SC_ITERS];
#pragma unroll
  for (int it = 0; it < SC_ITERS; ++it) {
    int e = lo + threadIdx.x + it * 256;
    kk[it] = (e < N) ? key[e] : 0xFFFFFFFFu;
  }
#pragma unroll
  for (int it = 0; it < SC_ITERS; ++it) {
    if (kk[it] != 0xFFFFFFFFu) rv[it] = rank[kk[it]];
  }
#pragma unroll
  for (int it = 0; it < SC_ITERS; ++it) {
    if (kk[it] != 0xFFFFFFFFu) {
      int e = lo + threadIdx.x + it * 256;
      inv[e] = rv[it];
      unsigned posn = atomicAdd(&ptStart[kk[it]], 1u);
      ptOrder[posn] = (unsigned)e;
    }
  }
}

// ---- 8 lanes per voxel: feature max (2x float4 per lane = full 256B row) + pos mean ----
__global__ void __launch_bounds__(256) k_pool(const float4* __restrict__ x4,
                                              const float* __restrict__ pos,
                                              const unsigned* __restrict__ ptOrder,
                                              const unsigned* __restrict__ cStart,
                                              const unsigned* __restrict__ hdr,
                                              float* __restrict__ out) {
  unsigned gtid = blockIdx.x * blockDim.x + threadIdx.x;
  unsigned m = gtid >> 3;     // voxel id
  unsigned l = gtid & 7u;     // lane-in-group
  unsigned M = hdr[3];
  if (m >= M) return;
  unsigned start = cStart[m];
  unsigned n = cStart[m + 1] - start;
  const float NI = -__builtin_huge_valf();
  float4 a0 = make_float4(NI, NI, NI, NI);
  float4 a1 = a0;
  float psum = 0.0f;
  for (unsigned j = 0; j < n; ++j) {
    unsigned p = ptOrder[start + j];
    float4 v0 = x4[p * 16u + l];
    float4 v1 = x4[p * 16u + 8u + l];
    a0.x = fmaxf(a0.x, v0.x); a0.y = fmaxf(a0.y, v0.y);
    a0.z = fmaxf(a0.z, v0.z); a0.w = fmaxf(a0.w, v0.w);
    a1.x = fmaxf(a1.x, v1.x); a1.y = fmaxf(a1.y, v1.y);
    a1.z = fmaxf(a1.z, v1.z); a1.w = fmaxf(a1.w, v1.w);
    if (l < 3) psum += pos[3u * p + l];
  }
  float4* o4 = (float4*)out;
  o4[m * 16u + l] = a0;
  o4[m * 16u + 8u + l] = a1;
  if (l < 3) {
    unsigned long long O1 = 64ull * M;
    out[O1 + 3ull * m + l] = psum / (float)n;
  }
}

// ---- edges: fine-partition histogram + code64 encode (coalesced stage0 write).
//      Self-loops counted/staged (filtered in k_bucket, where src is known). ----
__global__ void __launch_bounds__(256) k_ehist(const int2* __restrict__ ei,
                                               const unsigned* __restrict__ inv,
                                               unsigned* __restrict__ partCnt,
                                               unsigned long long* __restrict__ stage0, int E) {
  __shared__ unsigned h[NPART];
  for (int i = threadIdx.x; i < NPART; i += 256) h[i] = 0;
  __syncthreads();
  int lo = blockIdx.x * (256 * PS_ITERS);
  unsigned av[PS_ITERS], bv[PS_ITERS];
#pragma unroll
  for (int it = 0; it < PS_ITERS; ++it) {
    int e = lo + threadIdx.x + it * 256;
    if (e < E) { int2 pr = ei[e]; av[it] = (unsigned)pr.x; bv[it] = (unsigned)pr.y; }
    else av[it] = 0xFFFFFFFFu;
  }
#pragma unroll
  for (int it = 0; it < PS_ITERS; ++it) {
    if (av[it] != 0xFFFFFFFFu) { av[it] = inv[av[it]]; bv[it] = inv[bv[it]]; }
  }
#pragma unroll
  for (int it = 0; it < PS_ITERS; ++it) {
    if (av[it] != 0xFFFFFFFFu) {
      int e = lo + threadIdx.x + it * 256;
      stage0[e] = ((unsigned long long)av[it] << 19) | bv[it];
      atomicAdd(&h[av[it] >> PSHIFT], 1u);
    }
  }
  __syncthreads();
  for (int i = threadIdx.x; i < NPART; i += 256) {
    unsigned v = h[i];
    if (v) atomicAdd(&partCnt[i], v);
  }
}

// ---- edges pass 1: linear stage0 stream -> 64 coarse buckets;
//      code32 = (srcLow13<<19)|dst. No gathers. ----
__global__ void __launch_bounds__(256) k_pscat1(const unsigned long long* __restrict__ stage0,
                                                unsigned* __restrict__ ccur,
                                                unsigned* __restrict__ stage1, int E) {
  __shared__ unsigned h[NCOARSE];
  if (threadIdx.x < NCOARSE) h[threadIdx.x] = 0;
  __syncthreads();
  int lo = blockIdx.x * (256 * PS_ITERS);
  unsigned long long codes[PS_ITERS];
#pragma unroll
  for (int it = 0; it < PS_ITERS; ++it) {
    int e = lo + threadIdx.x + it * 256;
    codes[it] = (e < E) ? stage0[e] : ~0ull;
    if (codes[it] != ~0ull) {
      unsigned a = (unsigned)(codes[it] >> 19);
      atomicAdd(&h[a >> CSHIFT], 1u);
    }
  }
  __syncthreads();
  if (threadIdx.x < NCOARSE) {
    unsigned v = h[threadIdx.x];
    h[threadIdx.x] = v ? atomicAdd(&ccur[threadIdx.x], v) : 0u;
  }
  __syncthreads();
#pragma unroll
  for (int it = 0; it < PS_ITERS; ++it) {
    unsigned long long code = codes[it];
    if (code != ~0ull) {
      unsigned a = (unsigned)(code >> 19);
      unsigned off = atomicAdd(&h[a >> CSHIFT], 1u);
      stage1[off] = ((a & CMASK) << 19) | ((unsigned)code & 0x7FFFFu);
    }
  }
}

// ---- edges pass 2: coarse stream -> fine partitions (code27 into pStage). ----
__global__ void __launch_bounds__(256) k_pscat2(const unsigned* __restrict__ stage1,
                                                const unsigned* __restrict__ partStart,
                                                unsigned* __restrict__ partCursor,
                                                unsigned* __restrict__ pStage) {
  __shared__ unsigned h[NPART];
  __shared__ unsigned cbL[NCOARSE + 1];
  __shared__ unsigned c0s;
  for (int i = threadIdx.x; i < NPART; i += 256) h[i] = 0;
  if (threadIdx.x <= NCOARSE) cbL[threadIdx.x] = partStart[threadIdx.x << 5];
  __syncthreads();
  unsigned base = blockIdx.x * (256u * PS_ITERS);
  unsigned validE = cbL[NCOARSE];
  if (base >= validE) return;  // block-uniform exit
  if (threadIdx.x == 0) {
    unsigned c = 0;
    while (cbL[c + 1] <= base) ++c;
    c0s = c;
  }
  __syncthreads();
  unsigned codes[PS_ITERS], prt[PS_ITERS];
  unsigned c = c0s;
#pragma unroll
  for (int it = 0; it < PS_ITERS; ++it) {
    prt[it] = 0xFFFFFFFFu;
    unsigned g = base + threadIdx.x + it * 256u;
    if (g < validE) {
      while (cbL[c + 1] <= g) ++c;  // monotone in it
      unsigned code = stage1[g];
      codes[it] = code;
      unsigned part = (c << 5) | (code >> 27);
      prt[it] = part;
      atomicAdd(&h[part], 1u);
    }
  }
  __syncthreads();
  for (int i = threadIdx.x; i < NPART; i += 256) {
    unsigned v = h[i];
    h[i] = v ? atomicAdd(&partCursor[i], v) : 0u;
  }
  __syncthreads();
#pragma unroll
  for (int it = 0; it < PS_ITERS; ++it) {
    if (prt[it] != 0xFFFFFFFFu) {
      unsigned off = atomicAdd(&h[prt[it]], 1u);
      pStage[off] = codes[it] & 0x07FFFFFFu;
    }
  }
}

// ---- per-partition: LDS counting-sort by srcLow, element-parallel rank-sort by dst,
//      dedup+selfloop flag + block-scan compaction. LDS ~19.5KB -> 8 blocks/CU. ----
__global__ void __launch_bounds__(256) k_bucket(unsigned* __restrict__ pStage,
                                                const unsigned* __restrict__ partStart,
                                                unsigned* __restrict__ partDistinct) {
  __shared__ unsigned dstL[SCAP2];
  __shared__ unsigned h[PB];
  __shared__ unsigned bbase[PB + 1];
  __shared__ unsigned stmp[256];
  unsigned p = blockIdx.x;
  unsigned s = partStart[p];
  unsigned c = partStart[p + 1] - s;
  unsigned t = threadIdx.x;
  unsigned pb = p << PSHIFT;  // absolute src base of this partition
  h[t] = 0;  // PB == 256 == blockDim
  __syncthreads();
  if (c <= SCAP2) {
    const unsigned* src = pStage + s;
    // 1) histogram by srcLow
    for (unsigned i = t; i < c; i += 256) atomicAdd(&h[src[i] >> 19], 1u);
    __syncthreads();
    {  // 2) exclusive scan h -> bbase (256 entries, one per thread)
      unsigned v = h[t];
      stmp[t] = v;
      __syncthreads();
      for (int off = 1; off < 256; off <<= 1) {
        unsigned x = (t >= (unsigned)off) ? stmp[t - off] : 0u;
        __syncthreads(); stmp[t] += x; __syncthreads();
      }
      bbase[t] = stmp[t] - v;
      if (t == 255) bbase[PB] = stmp[255];
    }
    __syncthreads();
    h[t] = bbase[t];  // h becomes cursor
    __syncthreads();
    // 3) scatter code into bucket-contiguous LDS
    for (unsigned i = t; i < c; i += 256) {
      unsigned code = src[i];
      unsigned off = atomicAdd(&h[code >> 19], 1u);
      dstL[off] = code;
    }
    __syncthreads();
    // 4) element-parallel stable rank within bucket
    unsigned L = (c + 255) >> 8;  // elements per thread (blocked), <= 16
    unsigned vv[16], rr[16];
#pragma unroll
    for (unsigned k = 0; k < 16; ++k) {
      unsigned i = t * L + k;
      if (k < L && i < c) {
        unsigned v = dstL[i];
        unsigned b = v >> 19;
        unsigned blo = bbase[b], bhi = bbase[b + 1];
        unsigned r = blo;
        for (unsigned j = blo; j < bhi; ++j) {
          unsigned u = dstL[j];
          r += (u < v) || (u == v && j < i);
        }
        vv[k] = v; rr[k] = r;
      }
    }
    __syncthreads();
    // 5) in-place scatter to sorted position
#pragma unroll
    for (unsigned k = 0; k < 16; ++k) {
      unsigned i = t * L + k;
      if (k < L && i < c) dstL[rr[k]] = vv[k];
    }
    __syncthreads();
    // 6) dedup + self-loop flags (partition now sorted by code) + block scan
    unsigned flm = 0, localSum = 0;
#pragma unroll
    for (unsigned k = 0; k < 16; ++k) {
      unsigned i = t * L + k;
      if (k < L && i < c) {
        unsigned v = dstL[i];
        unsigned pv = dstL[i - (i > 0 ? 1u : 0u)];
        unsigned notself = ((v & 0x7FFFFu) != (pb | (v >> 19))) ? 1u : 0u;
        unsigned f = (((i == 0) | (pv != v)) ? 1u : 0u) & notself;
        flm |= f << k;
        localSum += f;
      }
    }
    stmp[t] = localSum;
    __syncthreads();
    for (int off = 1; off < 256; off <<= 1) {
      unsigned x = (t >= (unsigned)off) ? stmp[t - off] : 0u;
      __syncthreads(); stmp[t] += x; __syncthreads();
    }
    unsigned pos = stmp[t] - localSum;
    // 7) compact distinct codes back to pStage (sorted by (src,dst))
#pragma unroll
    for (unsigned k = 0; k < 16; ++k) {
      unsigned i = t * L + k;
      if (k < L && i < c && ((flm >> k) & 1u)) {
        pStage[s + pos] = dstL[i];
        ++pos;
      }
    }
    if (t == 255) partDistinct[p] = stmp[255];
  } else if (t == 0) {  // fallback, statistically unreachable
    unsigned* a = pStage + s;
    for (unsigned i = 1; i < c; ++i) {
      unsigned v = a[i];
      long long j = (long long)i - 1;
      while (j >= 0 && a[j] > v) { a[j + 1] = a[j]; --j; }
      a[j + 1] = v;
    }
    unsigned d = 0, prev = 0xFFFFFFFFu;
    for (unsigned i = 0; i < c; ++i) {
      unsigned v = a[i];
      if ((i == 0 || v != prev) && ((v & 0x7FFFFu) != (pb | (v >> 19)))) { a[d] = v; ++d; }
      prev = v;
    }
    partDistinct[p] = d;
  }
}

// ---- write deduped edges + self loops + new_batch (fused; one grid) ----
__global__ void __launch_bounds__(256) k_ewrite(const unsigned* __restrict__ pStage,
                                                const unsigned* __restrict__ partStart,
                                                const unsigned* __restrict__ partOut,
                                                const unsigned* __restrict__ ukeyArr,
                                                const unsigned* __restrict__ hdr,
                                                float* __restrict__ out) {
  unsigned M = hdr[3];
  unsigned long long O2 = 67ull * M;
  if (blockIdx.x < NPART) {
    unsigned p = blockIdx.x;
    unsigned s = partStart[p];
    unsigned rbase = partOut[p];
    unsigned d = partOut[p + 1] - rbase;
    unsigned pbase = p << PSHIFT;
    for (unsigned j = threadIdx.x; j < d; j += 256) {
      unsigned code = pStage[s + j];
      unsigned long long row = (unsigned long long)rbase + j;
      out[O2 + 2 * row + 0] = (float)(pbase | (code >> 19));
      out[O2 + 2 * row + 1] = (float)(code & 0x7FFFFu);
    }
  } else {
    unsigned m = (blockIdx.x - NPART) * 256 + threadIdx.x;
    if (m >= M) return;
    unsigned Ed = hdr[5];
    unsigned long long row = (unsigned long long)Ed + m;
    float fm = (float)m;
    out[O2 + 2 * row + 0] = fm;
    out[O2 + 2 * row + 1] = fm;
    unsigned long long O3 = O2 + 2ull * (Ed + M);
    out[O3 + m] = (float)(ukeyArr[m] >> 15);  // key / 32768 = batch id
  }
}

extern "C" void kernel_launch(void* const* d_in, const int* in_sizes, int n_in,
                              void* d_out, int out_size, void* d_ws, size_t ws_size,
                              hipStream_t stream) {
  const float* x = (const float*)d_in[0];
  const float* pos = (const float*)d_in[1];
  const int* ei = (const int*)d_in[2];
  const int* batch = (const int*)d_in[3];
  float* out = (float*)d_out;
  int N = in_sizes[3];
  int E = in_sizes[2] / 2;

  unsigned* ws = (unsigned*)d_ws;
  // ws layout (u32 units)
  unsigned* hdr          = ws;                        // 64
  unsigned* cnt          = ws + 64;                   // KSP
  unsigned* partCnt      = cnt + KSP;                 // NPART
  unsigned* partDistinct = partCnt + NPART;           // NPART
  unsigned* rank         = partDistinct + NPART;      // KSP
  unsigned* ukeyArr      = rank + KSP;                // KSP
  unsigned* cStart       = ukeyArr + KSP;             // KSP+2 (M+1 used)
  unsigned* partStart    = cStart + KSP + 2;          // NPART+2
  unsigned* partCursor   = partStart + NPART + 2;     // NPART
  unsigned* partOut      = partCursor + NPART;        // NPART+2
  unsigned* chunkP       = partOut + NPART + 2;       // 1024 (NCHUNK used)
  unsigned* chunkC       = chunkP + 1024;             // 1024
  unsigned* ccur         = chunkC + 1024;             // 66 (coarse cursors)
  unsigned* key          = ccur + 66;                 // N
  unsigned* inv          = key + N;                   // N
  unsigned* pS32         = inv + ((N + 1) & ~1);      // 8B-aligned scratch region
  // Aliased, stream-ordered lifetimes within the region at pS32 (3E u32 total):
  unsigned* ptStart  = pS32;                          // KSP  (dead after k_pool)
  unsigned* ptOrder  = pS32 + KSP;                    // N    (dead after k_pool)
  unsigned long long* stage0 = (unsigned long long*)pS32;  // E u64 (ehist->pscat1)
  unsigned* pStage   = pS32;                          // E u32 (pscat2 onward)
  unsigned* stage1   = pS32 + 2 * (size_t)E;          // E u32 (pscat1->pscat2)

  // zero: hdr + cnt + partCnt + partDistinct (contiguous).
  hipMemsetAsync(ws, 0, (size_t)(64 + KSP + 2 * NPART) * 4, stream);

  const int B = 256;
  int gN = (N + B - 1) / B;
  int gK = (KSP + B - 1) / B;
  int gP = (int)(((long long)N * 8 + B - 1) / B);  // k_pool: 8 lanes per voxel, M<=N
  int gS = (N + B * SC_ITERS - 1) / (B * SC_ITERS);       // k_scatter blocks
  int ebS = (E + 256 * PS_ITERS - 1) / (256 * PS_ITERS);  // ehist/pscat1/pscat2 blocks

  k_keys<<<gN, B, 0, stream>>>(pos, batch, key, cnt, N);

  // fused dual scan: rank (presence) + ptStart (counts); hdr[3] = M.
  // scanC2 also emits ukeyArr + cStart (fused k_ukey).
  scanA2<<<NCHUNK, SCAN_BLOCK, 0, stream>>>(cnt, rank, ptStart, chunkP, chunkC, KSP);
  scanB2<<<1, NCHUNK, 0, stream>>>(chunkP, chunkC, &hdr[3]);
  scanC2<<<gK, B, 0, stream>>>(rank, ptStart, chunkP, chunkC, cnt, hdr, ukeyArr, cStart,
                               KSP, N);

  k_scatter<<<gS, B, 0, stream>>>(key, rank, inv, ptStart, ptOrder, N);
  k_pool<<<gP, B, 0, stream>>>((const float4*)x, pos, ptOrder, cStart, hdr, out);

  // edges: hist+encode -> scan(+coarse cursors) -> coarse scatter -> fine scatter
  //        -> dedup -> write(+loops/batch)
  const int2* ei2 = (const int2*)ei;
  k_ehist<<<ebS, 256, 0, stream>>>(ei2, inv, partCnt, stage0, E);
  k_scanP<<<1, 1024, 0, stream>>>(partCnt, partStart, partCursor, ccur, &hdr[4]);
  k_pscat1<<<ebS, 256, 0, stream>>>(stage0, ccur, stage1, E);
  k_pscat2<<<ebS, 256, 0, stream>>>(stage1, partStart, partCursor, pStage);
  k_bucket<<<NPART, 256, 0, stream>>>(pStage, partStart, partDistinct);
  k_scanP<<<1, 1024, 0, stream>>>(partDistinct, partOut, nullptr, nullptr, &hdr[5]);
  k_ewrite<<<NPART + gK, 256, 0, stream>>>(pStage, partStart, partOut, ukeyArr, hdr, out);

  (void)n_in; (void)ws_size;
}